// Round 17
// baseline (972.545 us; speedup 1.0000x reference)
//
#include <hip/hip_runtime.h>
#include <hip/hip_fp16.h>

// ---------------- constants ----------------
namespace {
constexpr int NN = 50000;   // nodes
constexpr int NE = 800000;  // edges
constexpr int NG = 256;     // graphs
constexpr int NF = 34;      // in features
constexpr int NL = 4;       // GAT layers
constexpr int NB = (NN + 255) / 256;  // scan blocks = 196
}
#define EPSB 1e-5f
#define LSLOPE 0.2f
#define INV_SQRT_C 0.17677669529663687f  // 1/sqrt(32)

typedef short bf16x8 __attribute__((ext_vector_type(8)));
typedef float f32x4 __attribute__((ext_vector_type(4)));
typedef _Float16 hv2 __attribute__((ext_vector_type(2)));

static __device__ __forceinline__ short f2bf(float f) {
    unsigned int u = __float_as_uint(f);
    u = (u + 0x7fff + ((u >> 16) & 1)) >> 16;  // RNE
    return (short)u;
}
// order-preserving float<->uint for atomicMax; all encodings > 0, so memset-0 = -inf
static __device__ __forceinline__ unsigned fenc(float x) {
    unsigned u = __float_as_uint(x);
    return (u & 0x80000000u) ? ~u : (u | 0x80000000u);
}
static __device__ __forceinline__ float fdec(unsigned u) {
    return __uint_as_float((u & 0x80000000u) ? (u ^ 0x80000000u) : ~u);
}
// v_dot2_f32_f16: c += a.x*b.x + a.y*b.y (fp32 accumulate)
static __device__ __forceinline__ float fdot2(hv2 a, hv2 b, float c) {
    return __builtin_amdgcn_fdot2(a, b, c, false);
}

// ---------------- CSR build: 4 DISJOINT strands/thread (tid<S guard is load-bearing)
__global__ __launch_bounds__(256) void k_deg(const int* __restrict__ ei,
                                             int* __restrict__ deg,
                                             int* __restrict__ rank) {
    int tid = blockIdx.x * 256 + threadIdx.x;
    const int S = (NE + 3) / 4;  // 200000
    if (tid >= S) return;
#pragma unroll
    for (int k = 0; k < 4; ++k) {
        int e = tid + k * S;
        if (e < NE) rank[e] = atomicAdd(&deg[ei[NE + e]], 1);
    }
}

__global__ __launch_bounds__(256) void k_scan1(const int* __restrict__ deg, int* __restrict__ bsum) {
    __shared__ int sm[256];
    int i = blockIdx.x * 256 + threadIdx.x;
    sm[threadIdx.x] = (i < NN) ? deg[i] : 0;
    __syncthreads();
    for (int off = 128; off > 0; off >>= 1) {
        if (threadIdx.x < off) sm[threadIdx.x] += sm[threadIdx.x + off];
        __syncthreads();
    }
    if (threadIdx.x == 0) bsum[blockIdx.x] = sm[0];
}

__global__ __launch_bounds__(256) void k_scan2(const int* __restrict__ bsum,
                                               int* __restrict__ boff, int* __restrict__ rp) {
    __shared__ int sm[256];
    int t = threadIdx.x;
    int v = (t < NB) ? bsum[t] : 0;
    sm[t] = v;
    __syncthreads();
    for (int off = 1; off < 256; off <<= 1) {
        int u = (t >= off) ? sm[t - off] : 0;
        __syncthreads();
        sm[t] += u;
        __syncthreads();
    }
    if (t < NB) boff[t] = sm[t] - v;
    if (t == 255) rp[NN] = sm[255];
}

__global__ __launch_bounds__(256) void k_scan3(const int* __restrict__ deg,
                                               const int* __restrict__ boff,
                                               int* __restrict__ rp) {
    __shared__ int sm[256];
    int i = blockIdx.x * 256 + threadIdx.x;
    int t = threadIdx.x;
    int v = (i < NN) ? deg[i] : 0;
    sm[t] = v;
    __syncthreads();
    for (int off = 1; off < 256; off <<= 1) {
        int u = (t >= off) ? sm[t - off] : 0;
        __syncthreads();
        sm[t] += u;
        __syncthreads();
    }
    if (i < NN) rp[i] = boff[blockIdx.x] + sm[t] - v;
}

// atomic-free scatter: p = rp[d] + rank[e]; 4 disjoint strands per thread
__global__ __launch_bounds__(256) void k_fill(const int* __restrict__ ei,
                                              const int* __restrict__ rp,
                                              const int* __restrict__ rank,
                                              int2* __restrict__ edg) {
    int tid = blockIdx.x * 256 + threadIdx.x;
    const int S = (NE + 3) / 4;
    if (tid >= S) return;
#pragma unroll
    for (int k = 0; k < 4; ++k) {
        int e = tid + k * S;
        if (e < NE) {
            int s = ei[e];
            int d = ei[NE + e];
            int p = rp[d] + rank[e];
            edg[p] = make_int2(s, d);
        }
    }
}

// ---------------- weight prep: 12x (128,128) fp32 -> transposed bf16 ----------------
__global__ __launch_bounds__(256) void k_prep(const float* __restrict__ gWl,
                                              const float* __restrict__ gWr,
                                              const float* __restrict__ tWq,
                                              const float* __restrict__ tWk,
                                              const float* __restrict__ tWv,
                                              const float* __restrict__ tWs,
                                              short* __restrict__ dst) {
    int m = blockIdx.x;
    const float* src;
    if (m < 4) src = gWl + m * 16384;
    else if (m < 8) src = gWr + (m - 4) * 16384;
    else if (m == 8) src = tWq;
    else if (m == 9) src = tWk;
    else if (m == 10) src = tWv;
    else src = tWs;
    short* d = dst + m * 16384;
    for (int i = threadIdx.x; i < 16384; i += 256) {
        int n = i >> 7, k = i & 127;
        d[i] = f2bf(src[k * 128 + n]);  // Wt[n][k] = W[k][n]
    }
}

// ------- pair-fused MFMA GEMM with FUSED BN(+ReLU)+residual in the A-stage ----------
template <int OUTH0, int OUTH1, int RES, int XOUT>
__global__ __launch_bounds__(256) void k_gemm2bn(const float* __restrict__ src,
                                                 const float* __restrict__ res,
                                                 float* __restrict__ xout,
                                                 const float* __restrict__ st,
                                                 const float* __restrict__ g,
                                                 const float* __restrict__ b,
                                                 const short* __restrict__ Wt0,
                                                 const short* __restrict__ Wt1,
                                                 const float* __restrict__ bias0,
                                                 const float* __restrict__ bias1,
                                                 void* __restrict__ out0,
                                                 void* __restrict__ out1, int nRows) {
    __shared__ short As[128 * 136];
    __shared__ short Bs[128 * 136];
    __shared__ float scsh[256];
    const float invn = 1.f / NN;
    if (threadIdx.x < 128) {
        int c = threadIdx.x;
        float mean = st[c] * invn;
        float var = fmaxf(st[128 + c] * invn - mean * mean, 0.f);
        float s = g[c] * rsqrtf(var + EPSB);
        scsh[c] = s;
        scsh[128 + c] = b[c] - mean * s;
    }
    {
        const int4* Wt4 = (const int4*)Wt0;
        for (int idx = threadIdx.x; idx < 2048; idx += 256) {
            int row = idx >> 4, c8 = idx & 15;
            *(int4*)&Bs[row * 136 + c8 * 8] = Wt4[idx];
        }
    }
    __syncthreads();  // scsh ready
    int r0 = blockIdx.x * 128;
    int rows = nRows - r0; if (rows > 128) rows = 128;
    for (int idx = threadIdx.x; idx < 2048; idx += 256) {
        int r = idx >> 4, c8 = idx & 15;
        short4 sa = {0, 0, 0, 0}, sb = {0, 0, 0, 0};
        if (r < rows) {
            size_t base = (size_t)(r0 + r) * 128 + c8 * 8;
            float4 v0 = *(const float4*)&src[base];
            float4 v1 = *(const float4*)&src[base + 4];
            int c = c8 * 8;
            v0.x = fmaxf(v0.x * scsh[c + 0] + scsh[128 + c + 0], 0.f);
            v0.y = fmaxf(v0.y * scsh[c + 1] + scsh[128 + c + 1], 0.f);
            v0.z = fmaxf(v0.z * scsh[c + 2] + scsh[128 + c + 2], 0.f);
            v0.w = fmaxf(v0.w * scsh[c + 3] + scsh[128 + c + 3], 0.f);
            v1.x = fmaxf(v1.x * scsh[c + 4] + scsh[128 + c + 4], 0.f);
            v1.y = fmaxf(v1.y * scsh[c + 5] + scsh[128 + c + 5], 0.f);
            v1.z = fmaxf(v1.z * scsh[c + 6] + scsh[128 + c + 6], 0.f);
            v1.w = fmaxf(v1.w * scsh[c + 7] + scsh[128 + c + 7], 0.f);
            if (RES) {
                float4 rr0 = *(const float4*)&res[base];
                float4 rr1 = *(const float4*)&res[base + 4];
                v0.x += rr0.x; v0.y += rr0.y; v0.z += rr0.z; v0.w += rr0.w;
                v1.x += rr1.x; v1.y += rr1.y; v1.z += rr1.z; v1.w += rr1.w;
            }
            if (XOUT) {
                *(float4*)&xout[base] = v0;
                *(float4*)&xout[base + 4] = v1;
            }
            sa.x = f2bf(v0.x); sa.y = f2bf(v0.y); sa.z = f2bf(v0.z); sa.w = f2bf(v0.w);
            sb.x = f2bf(v1.x); sb.y = f2bf(v1.y); sb.z = f2bf(v1.z); sb.w = f2bf(v1.w);
        }
        *(short4*)&As[r * 136 + c8 * 8] = sa;
        *(short4*)&As[r * 136 + c8 * 8 + 4] = sb;
    }
    __syncthreads();
    int lane = threadIdx.x & 63, wave = threadIdx.x >> 6;
    int n16 = lane & 15, quad = lane >> 4;
    bf16x8 af[2][4];
#pragma unroll
    for (int rt = 0; rt < 2; ++rt)
#pragma unroll
        for (int kc = 0; kc < 4; ++kc)
            af[rt][kc] = *(const bf16x8*)&As[(wave * 32 + rt * 16 + n16) * 136 + kc * 32 + quad * 8];

    f32x4 acc[2][8];
#pragma unroll
    for (int rt = 0; rt < 2; ++rt)
#pragma unroll
        for (int ct = 0; ct < 8; ++ct) acc[rt][ct] = (f32x4){0.f, 0.f, 0.f, 0.f};
#pragma unroll
    for (int ct = 0; ct < 8; ++ct)
#pragma unroll
        for (int kc = 0; kc < 4; ++kc) {
            bf16x8 bf = *(const bf16x8*)&Bs[(ct * 16 + n16) * 136 + kc * 32 + quad * 8];
            acc[0][ct] = __builtin_amdgcn_mfma_f32_16x16x32_bf16(af[0][kc], bf, acc[0][ct], 0, 0, 0);
            acc[1][ct] = __builtin_amdgcn_mfma_f32_16x16x32_bf16(af[1][kc], bf, acc[1][ct], 0, 0, 0);
        }
#pragma unroll
    for (int ct = 0; ct < 8; ++ct) {
        int colI = ct * 16 + n16;
        float bv = bias0[colI];
#pragma unroll
        for (int rt = 0; rt < 2; ++rt)
#pragma unroll
            for (int reg = 0; reg < 4; ++reg) {
                int r = wave * 32 + rt * 16 + quad * 4 + reg;  // C/D: col=lane&15, row=quad*4+reg
                if (r < rows) {
                    float v = acc[rt][ct][reg] + bv;
                    if (OUTH0) ((__half*)out0)[(size_t)(r0 + r) * 128 + colI] = __float2half(v);
                    else       ((float*)out0)[(size_t)(r0 + r) * 128 + colI] = v;
                }
            }
    }
    __syncthreads();
    {
        const int4* Wt4 = (const int4*)Wt1;
        for (int idx = threadIdx.x; idx < 2048; idx += 256) {
            int row = idx >> 4, c8 = idx & 15;
            *(int4*)&Bs[row * 136 + c8 * 8] = Wt4[idx];
        }
    }
    __syncthreads();
#pragma unroll
    for (int rt = 0; rt < 2; ++rt)
#pragma unroll
        for (int ct = 0; ct < 8; ++ct) acc[rt][ct] = (f32x4){0.f, 0.f, 0.f, 0.f};
#pragma unroll
    for (int ct = 0; ct < 8; ++ct)
#pragma unroll
        for (int kc = 0; kc < 4; ++kc) {
            bf16x8 bf = *(const bf16x8*)&Bs[(ct * 16 + n16) * 136 + kc * 32 + quad * 8];
            acc[0][ct] = __builtin_amdgcn_mfma_f32_16x16x32_bf16(af[0][kc], bf, acc[0][ct], 0, 0, 0);
            acc[1][ct] = __builtin_amdgcn_mfma_f32_16x16x32_bf16(af[1][kc], bf, acc[1][ct], 0, 0, 0);
        }
#pragma unroll
    for (int ct = 0; ct < 8; ++ct) {
        int colI = ct * 16 + n16;
        float bv = bias1[colI];
#pragma unroll
        for (int rt = 0; rt < 2; ++rt)
#pragma unroll
            for (int reg = 0; reg < 4; ++reg) {
                int r = wave * 32 + rt * 16 + quad * 4 + reg;
                if (r < rows) {
                    float v = acc[rt][ct][reg] + bv;
                    if (OUTH1) ((__half*)out1)[(size_t)(r0 + r) * 128 + colI] = __float2half(v);
                    else       ((float*)out1)[(size_t)(r0 + r) * 128 + colI] = v;
                }
            }
    }
}

// ---------------- GEMM: (n,34) @ (34,128) + bias (fp32 VALU) ----------
__global__ __launch_bounds__(256) void k_gemm_emb(const float* __restrict__ A,
                                                  const float* __restrict__ W,
                                                  const float* __restrict__ bias,
                                                  float* __restrict__ out, int nRows) {
    __shared__ float As[64 * NF];
    int r0 = blockIdx.x * 64;
    int rows = nRows - r0; if (rows > 64) rows = 64;
    int total = rows * NF;
    for (int idx = threadIdx.x; idx < 64 * NF; idx += 256)
        As[idx] = (idx < total) ? A[(size_t)r0 * NF + idx] : 0.f;
    __syncthreads();
    int tx = threadIdx.x & 31, ty = threadIdx.x >> 5;
    const float4* W4 = (const float4*)W;
    float acc[8][4];
#pragma unroll
    for (int j = 0; j < 8; ++j)
#pragma unroll
        for (int i = 0; i < 4; ++i) acc[j][i] = 0.f;
#pragma unroll 2
    for (int k = 0; k < NF; ++k) {
        float4 w = W4[k * 32 + tx];
#pragma unroll
        for (int j = 0; j < 8; ++j) {
            float a = As[(ty * 8 + j) * NF + k];
            acc[j][0] += a * w.x; acc[j][1] += a * w.y;
            acc[j][2] += a * w.z; acc[j][3] += a * w.w;
        }
    }
    float4 b = ((const float4*)bias)[tx];
#pragma unroll
    for (int j = 0; j < 8; ++j) {
        int r = ty * 8 + j;
        if (r < rows) {
            float4 o = make_float4(acc[j][0] + b.x, acc[j][1] + b.y,
                                   acc[j][2] + b.z, acc[j][3] + b.w);
            ((float4*)out)[(size_t)(r0 + r) * 32 + tx] = o;
        }
    }
}

// ---------------- BN statistics (per-column sum / sumsq) ----------------
__global__ __launch_bounds__(256) void k_stats(const float* __restrict__ src, int nRows,
                                               float* __restrict__ st) {
    int c = threadIdx.x & 127;
    int sub = threadIdx.x >> 7;  // 0/1
    int r0 = blockIdx.x * 128;
    int rend = r0 + 128; if (rend > nRows) rend = nRows;
    float s = 0.f, ss = 0.f;
    for (int r = r0 + sub; r < rend; r += 2) {
        float v = src[(size_t)r * 128 + c];
        s += v; ss += v * v;
    }
    atomicAdd(&st[c], s);
    atomicAdd(&st[128 + c], ss);
}

// final (non-ReLU) BN: dst = res + bn(src)
__global__ __launch_bounds__(256) void k_bn_final(float* __restrict__ dst,
                                                  const float* __restrict__ src,
                                                  const float* __restrict__ res,
                                                  const float* __restrict__ st,
                                                  const float* __restrict__ g,
                                                  const float* __restrict__ b) {
    int tid = blockIdx.x * blockDim.x + threadIdx.x;
    int cb = (tid & 31) * 4;
    const float invn = 1.f / NN;
    float sc[4], sh[4];
#pragma unroll
    for (int k = 0; k < 4; ++k) {
        float mean = st[cb + k] * invn;
        float var = fmaxf(st[128 + cb + k] * invn - mean * mean, 0.f);
        float s = g[cb + k] * rsqrtf(var + EPSB);
        sc[k] = s; sh[k] = b[cb + k] - mean * s;
    }
    const float4* s4 = (const float4*)src;
    const float4* r4 = (const float4*)res;
    float4* d4 = (float4*)dst;
    const int total = NN * 32;
    for (int i = tid; i < total; i += gridDim.x * blockDim.x) {
        float4 v = s4[i];
        float4 rr = r4[i];
        v.x = v.x * sc[0] + sh[0] + rr.x;
        v.y = v.y * sc[1] + sh[1] + rr.y;
        v.z = v.z * sc[2] + sh[2] + rr.z;
        v.w = v.w * sc[3] + sh[3] + rr.w;
        d4[i] = v;
    }
}

// ---- FUSED GAT edge pass: EIGHTH-wave per edge (8 lanes x 16 chans), fp16 score ----
// head = l8>>1 (2 lanes/head); dot reduction = 1 shfl_xor. 8 edges/wave in flight.
__global__ __launch_bounds__(256) void k_gat_aggr(const __half* __restrict__ xl,
                                                  const __half* __restrict__ xr,
                                                  const float* __restrict__ att,
                                                  const float* __restrict__ gbias_l,
                                                  const int* __restrict__ rp,
                                                  const int2* __restrict__ edg,
                                                  float* __restrict__ out) {
    int lane = threadIdx.x & 63;
    int node = blockIdx.x * 4 + (threadIdx.x >> 6);
    if (node >= NN) return;
    int o = lane >> 3;      // edge strand 0..7
    int l8 = lane & 7;
    int c16 = l8 * 16;
    // preload xr[node] (16 chans) and att (16 chans)
    float4 xrA = *(const float4*)&xr[(unsigned)node * 128u + c16];
    float4 xrB = *(const float4*)&xr[(unsigned)node * 128u + c16 + 8];
    hv2 xrh[8] = {*(hv2*)&xrA.x, *(hv2*)&xrA.y, *(hv2*)&xrA.z, *(hv2*)&xrA.w,
                  *(hv2*)&xrB.x, *(hv2*)&xrB.y, *(hv2*)&xrB.z, *(hv2*)&xrB.w};
    hv2 ath[8];
#pragma unroll
    for (int k = 0; k < 4; ++k) {
        float2 a2 = *(const float2*)&att[c16 + 2 * k];
        ath[k] = hv2{(_Float16)a2.x, (_Float16)a2.y};
        float2 b2 = *(const float2*)&att[c16 + 8 + 2 * k];
        ath[4 + k] = hv2{(_Float16)b2.x, (_Float16)b2.y};
    }
    const hv2 hz = {(_Float16)0.f, (_Float16)0.f};
    const hv2 hs = {(_Float16)LSLOPE, (_Float16)LSLOPE};
    int s0 = rp[node];
    int T = rp[node + 1] - s0 + 1;  // logical edge T-1 is the self loop
    float a[16];
#pragma unroll
    for (int k = 0; k < 16; ++k) a[k] = 0.f;
    float l = 0.f;
    auto body = [&](int j) {
        bool self = (j == T - 1);
        int src = self ? node : edg[s0 + j].x;
        float4 rawA = *(const float4*)&xl[(unsigned)src * 128u + c16];
        float4 rawB = *(const float4*)&xl[(unsigned)src * 128u + c16 + 8];
        hv2 f[8] = {*(hv2*)&rawA.x, *(hv2*)&rawA.y, *(hv2*)&rawA.z, *(hv2*)&rawA.w,
                    *(hv2*)&rawB.x, *(hv2*)&rawB.y, *(hv2*)&rawB.z, *(hv2*)&rawB.w};
        float p = 0.f;
#pragma unroll
        for (int k = 0; k < 8; ++k) {
            hv2 e = f[k] + xrh[k];
            hv2 lk = __builtin_elementwise_max(e, hz) + hs * __builtin_elementwise_min(e, hz);
            p = fdot2(lk, ath[k], p);
        }
        p += __shfl_xor(p, 1);  // head = l8>>1: pair l8^1 completes the 32-chan dot
        float w = __expf(p);
#pragma unroll
        for (int k = 0; k < 8; ++k) {
            a[2 * k] += w * (float)f[k].x;
            a[2 * k + 1] += w * (float)f[k].y;
        }
        l += w;
    };
    int j = o;
    for (; j + 8 < T; j += 16) { body(j); body(j + 8); }
    for (; j < T; j += 8) body(j);
#pragma unroll
    for (int k = 0; k < 16; ++k) {
        a[k] += __shfl_xor(a[k], 8); a[k] += __shfl_xor(a[k], 16); a[k] += __shfl_xor(a[k], 32);
    }
    l += __shfl_xor(l, 8); l += __shfl_xor(l, 16); l += __shfl_xor(l, 32);
    if (o == 0) {
        float inv = 1.f / (l + 1e-16f);
        float4 gb0 = *(const float4*)&gbias_l[c16];
        float4 gb1 = *(const float4*)&gbias_l[c16 + 4];
        float4 gb2 = *(const float4*)&gbias_l[c16 + 8];
        float4 gb3 = *(const float4*)&gbias_l[c16 + 12];
        float4 o0 = make_float4(a[0] * inv + gb0.x, a[1] * inv + gb0.y, a[2] * inv + gb0.z, a[3] * inv + gb0.w);
        float4 o1 = make_float4(a[4] * inv + gb1.x, a[5] * inv + gb1.y, a[6] * inv + gb1.z, a[7] * inv + gb1.w);
        float4 o2 = make_float4(a[8] * inv + gb2.x, a[9] * inv + gb2.y, a[10] * inv + gb2.z, a[11] * inv + gb2.w);
        float4 o3 = make_float4(a[12] * inv + gb3.x, a[13] * inv + gb3.y, a[14] * inv + gb3.z, a[15] * inv + gb3.w);
        *(float4*)&out[(unsigned)node * 128u + c16] = o0;
        *(float4*)&out[(unsigned)node * 128u + c16 + 4] = o1;
        *(float4*)&out[(unsigned)node * 128u + c16 + 8] = o2;
        *(float4*)&out[(unsigned)node * 128u + c16 + 12] = o3;
    }
}

// ---- FUSED Transformer edge pass: eighth-wave per edge, fdot2 QK, fp16 skip --------
__global__ __launch_bounds__(256) void k_trans_aggr(const __half* __restrict__ qh,
                                                    const __half* __restrict__ kh,
                                                    const __half* __restrict__ vv,
                                                    const __half* __restrict__ sT,
                                                    const int* __restrict__ rp,
                                                    const int2* __restrict__ edg,
                                                    float* __restrict__ out) {
    int lane = threadIdx.x & 63;
    int node = blockIdx.x * 4 + (threadIdx.x >> 6);
    if (node >= NN) return;
    int o = lane >> 3;
    int l8 = lane & 7;
    int c16 = l8 * 16;
    float4 qA = *(const float4*)&qh[(unsigned)node * 128u + c16];
    float4 qB = *(const float4*)&qh[(unsigned)node * 128u + c16 + 8];
    const hv2 hinv = {(_Float16)INV_SQRT_C, (_Float16)INV_SQRT_C};
    hv2 qv[8] = {(*(hv2*)&qA.x) * hinv, (*(hv2*)&qA.y) * hinv, (*(hv2*)&qA.z) * hinv, (*(hv2*)&qA.w) * hinv,
                 (*(hv2*)&qB.x) * hinv, (*(hv2*)&qB.y) * hinv, (*(hv2*)&qB.z) * hinv, (*(hv2*)&qB.w) * hinv};
    int s0 = rp[node];
    int T = rp[node + 1] - s0;
    float a[16];
#pragma unroll
    for (int k = 0; k < 16; ++k) a[k] = 0.f;
    float l = 0.f;
    auto body = [&](int j) {
        int src = edg[s0 + j].x;
        float4 kA = *(const float4*)&kh[(unsigned)src * 128u + c16];
        float4 kB = *(const float4*)&kh[(unsigned)src * 128u + c16 + 8];
        float4 vA = *(const float4*)&vv[(unsigned)src * 128u + c16];
        float4 vB = *(const float4*)&vv[(unsigned)src * 128u + c16 + 8];
        hv2 kv[8] = {*(hv2*)&kA.x, *(hv2*)&kA.y, *(hv2*)&kA.z, *(hv2*)&kA.w,
                     *(hv2*)&kB.x, *(hv2*)&kB.y, *(hv2*)&kB.z, *(hv2*)&kB.w};
        float p = 0.f;
#pragma unroll
        for (int k = 0; k < 8; ++k) p = fdot2(kv[k], qv[k], p);
        p += __shfl_xor(p, 1);
        float w = __expf(p);
        hv2 vvv[8] = {*(hv2*)&vA.x, *(hv2*)&vA.y, *(hv2*)&vA.z, *(hv2*)&vA.w,
                      *(hv2*)&vB.x, *(hv2*)&vB.y, *(hv2*)&vB.z, *(hv2*)&vB.w};
#pragma unroll
        for (int k = 0; k < 8; ++k) {
            a[2 * k] += w * (float)vvv[k].x;
            a[2 * k + 1] += w * (float)vvv[k].y;
        }
        l += w;
    };
    int j = o;
    for (; j + 8 < T; j += 16) { body(j); body(j + 8); }
    for (; j < T; j += 8) body(j);
#pragma unroll
    for (int k = 0; k < 16; ++k) {
        a[k] += __shfl_xor(a[k], 8); a[k] += __shfl_xor(a[k], 16); a[k] += __shfl_xor(a[k], 32);
    }
    l += __shfl_xor(l, 8); l += __shfl_xor(l, 16); l += __shfl_xor(l, 32);
    if (o == 0) {
        float inv = 1.f / (l + 1e-16f);
        float4 sA = *(const float4*)&sT[(unsigned)node * 128u + c16];
        float4 sB = *(const float4*)&sT[(unsigned)node * 128u + c16 + 8];
        hv2 st[8] = {*(hv2*)&sA.x, *(hv2*)&sA.y, *(hv2*)&sA.z, *(hv2*)&sA.w,
                     *(hv2*)&sB.x, *(hv2*)&sB.y, *(hv2*)&sB.z, *(hv2*)&sB.w};
        float4 o0 = make_float4(a[0] * inv + (float)st[0].x, a[1] * inv + (float)st[0].y,
                                a[2] * inv + (float)st[1].x, a[3] * inv + (float)st[1].y);
        float4 o1 = make_float4(a[4] * inv + (float)st[2].x, a[5] * inv + (float)st[2].y,
                                a[6] * inv + (float)st[3].x, a[7] * inv + (float)st[3].y);
        float4 o2 = make_float4(a[8] * inv + (float)st[4].x, a[9] * inv + (float)st[4].y,
                                a[10] * inv + (float)st[5].x, a[11] * inv + (float)st[5].y);
        float4 o3 = make_float4(a[12] * inv + (float)st[6].x, a[13] * inv + (float)st[6].y,
                                a[14] * inv + (float)st[7].x, a[15] * inv + (float)st[7].y);
        *(float4*)&out[(unsigned)node * 128u + c16] = o0;
        *(float4*)&out[(unsigned)node * 128u + c16 + 4] = o1;
        *(float4*)&out[(unsigned)node * 128u + c16 + 8] = o2;
        *(float4*)&out[(unsigned)node * 128u + c16 + 12] = o3;
    }
}

// ---------------- pooling phase 1: node-parallel partials (batch sorted) ------------
__global__ __launch_bounds__(256) void k_pool_part(const float* __restrict__ x,
                                                   const int* __restrict__ batch,
                                                   float* __restrict__ psum,
                                                   unsigned* __restrict__ pmax) {
    __shared__ int bs[64];
    int r0 = blockIdx.x * 64;
    if (threadIdx.x < 64) {
        int r = r0 + threadIdx.x;
        bs[threadIdx.x] = (r < NN) ? batch[r] : -1;
    }
    __syncthreads();
    int c = threadIdx.x & 127;
    int sub = threadIdx.x >> 7;
    int curg = -1;
    float s = 0.f, fmx = -INFINITY;
    for (int i = sub; i < 64; i += 2) {
        int r = r0 + i;
        if (r >= NN) break;
        int g = bs[i];
        if (g != curg) {
            if (curg >= 0) {
                atomicAdd(&psum[curg * 128 + c], s);
                atomicMax(&pmax[curg * 128 + c], fenc(fmx));
            }
            curg = g; s = 0.f; fmx = -INFINITY;
        }
        float v = x[(size_t)r * 128 + c];
        s += v; fmx = fmaxf(fmx, v);
    }
    if (curg >= 0) {
        atomicAdd(&psum[curg * 128 + c], s);
        atomicMax(&pmax[curg * 128 + c], fenc(fmx));
    }
}

// ---------------- pooling phase 2: finalize ----------------
__global__ __launch_bounds__(128) void k_pool_final(const float* __restrict__ psum,
                                                    const unsigned* __restrict__ pmax,
                                                    const int* __restrict__ batch,
                                                    float* __restrict__ h) {
    __shared__ int se[2];
    int g = blockIdx.x;
    if (threadIdx.x == 0) {
        int lo = 0, hi = NN;
        while (lo < hi) { int mid = (lo + hi) >> 1; if (batch[mid] < g) lo = mid + 1; else hi = mid; }
        se[0] = lo;
        hi = NN;
        while (lo < hi) { int mid = (lo + hi) >> 1; if (batch[mid] < g + 1) lo = mid + 1; else hi = mid; }
        se[1] = lo;
    }
    __syncthreads();
    int cnt = se[1] - se[0];
    int c = threadIdx.x;
    float xm = psum[g * 128 + c] / fmaxf((float)cnt, 1.f);
    float xx = (cnt > 0) ? fdec(pmax[g * 128 + c]) : 0.f;
    h[g * 256 + c] = xm;
    h[g * 256 + 128 + c] = xx;
}

// ---------------- head ----------------
__global__ __launch_bounds__(128) void k_head1(const float* __restrict__ h,
                                               const float* __restrict__ W,
                                               const float* __restrict__ b,
                                               float* __restrict__ t1) {
    __shared__ float hr[256];
    int row = blockIdx.x;
    int t = threadIdx.x;
    hr[t] = h[row * 256 + t];
    hr[t + 128] = h[row * 256 + 128 + t];
    __syncthreads();
    float acc = b[t];
#pragma unroll 4
    for (int k = 0; k < 256; ++k) acc += hr[k] * W[k * 128 + t];
    t1[row * 128 + t] = acc;
}

__global__ __launch_bounds__(64) void k_head2(const float* __restrict__ t1,
                                              const float* __restrict__ st,
                                              const float* __restrict__ og,
                                              const float* __restrict__ obe,
                                              const float* __restrict__ W2,
                                              const float* __restrict__ b2,
                                              const float* __restrict__ W3,
                                              const float* __restrict__ b3,
                                              float* __restrict__ out) {
    __shared__ float v[128];
    int row = blockIdx.x, t = threadIdx.x;
    const float invn = 1.f / NG;
#pragma unroll
    for (int half = 0; half < 2; ++half) {
        int ch = t + half * 64;
        float mean = st[ch] * invn;
        float var = fmaxf(st[128 + ch] * invn - mean * mean, 0.f);
        float scv = og[ch] * rsqrtf(var + EPSB);
        float shv = obe[ch] - mean * scv;
        float a = t1[row * 128 + ch] * scv + shv;
        v[ch] = fmaxf(a, 0.f);
    }
    __syncthreads();
    float acc = b2[t];
#pragma unroll 4
    for (int k = 0; k < 128; ++k) acc += v[k] * W2[k * 64 + t];
    float p = fmaxf(acc, 0.f) * W3[t];
    p += __shfl_xor(p, 1); p += __shfl_xor(p, 2); p += __shfl_xor(p, 4);
    p += __shfl_xor(p, 8); p += __shfl_xor(p, 16); p += __shfl_xor(p, 32);
    if (t == 0) out[row] = p + b3[0];
}

// ---------------- launch ----------------
extern "C" void kernel_launch(void* const* d_in, const int* in_sizes, int n_in,
                              void* d_out, int out_size, void* d_ws, size_t ws_size,
                              hipStream_t stream) {
    const float* x_in   = (const float*)d_in[0];
    const int*   ei     = (const int*)d_in[1];
    const int*   batch  = (const int*)d_in[2];
    const float* emb_W  = (const float*)d_in[3];
    const float* emb_b  = (const float*)d_in[4];
    const float* emb_g  = (const float*)d_in[5];
    const float* emb_be = (const float*)d_in[6];
    const float* gWl    = (const float*)d_in[7];
    const float* gWr    = (const float*)d_in[8];
    const float* gbl    = (const float*)d_in[9];
    const float* gbr    = (const float*)d_in[10];
    const float* gatt   = (const float*)d_in[11];
    const float* gbias  = (const float*)d_in[12];
    const float* gg     = (const float*)d_in[13];
    const float* gbe    = (const float*)d_in[14];
    const float* tWq    = (const float*)d_in[15];
    const float* tWk    = (const float*)d_in[16];
    const float* tWv    = (const float*)d_in[17];
    const float* tWs    = (const float*)d_in[18];
    const float* tbq    = (const float*)d_in[19];
    const float* tbk    = (const float*)d_in[20];
    const float* tbv    = (const float*)d_in[21];
    const float* tbs    = (const float*)d_in[22];
    const float* tg     = (const float*)d_in[23];
    const float* tbe    = (const float*)d_in[24];
    const float* oW1    = (const float*)d_in[25];
    const float* ob1    = (const float*)d_in[26];
    const float* og     = (const float*)d_in[27];
    const float* obe    = (const float*)d_in[28];
    const float* oW2    = (const float*)d_in[29];
    const float* ob2    = (const float*)d_in[30];
    const float* oW3    = (const float*)d_in[31];
    const float* ob3    = (const float*)d_in[32];
    float* out = (float*)d_out;

    const size_t NDsz = (size_t)NN * 128;
    float* x     = (float*)d_ws;       // ping
    float* bA    = x + NDsz;           // pong (also emb out, final pooled input)
    float* bC    = bA + NDsz;          // aggr output / pre-BN
    float* stats = bC + NDsz;          // 7 * 256 floats
    float* hpool = stats + 7 * 256;    // 256*256
    float* t1    = hpool + 65536;      // 256*128
    float* scb   = t1 + 32768;         // hosts rank (NE ints)
    __half* xlh  = (__half*)(scb + (size_t)(NE + NN) * 4);  // xl / K
    __half* xrh  = xlh + NDsz;         // xr / Q
    __half* vh   = xrh + NDsz;         // V
    __half* sh   = vh + NDsz;          // S skip (fp16)
    short* Wt    = (short*)(sh + NDsz);  // 12 * 128*128 bf16 transposed
    int* deg     = (int*)(Wt + 12 * 16384);
    int* rp      = deg + NN;
    int* cursor  = rp + NN + 1;        // kept (dead) to preserve proven layout
    int2* edg    = (int2*)(cursor + NN);  // NE+64 packed (src,dst)
    int* bsum    = (int*)(edg + NE + 64);
    int* boff    = bsum + 256;
    float* psum  = (float*)(boff + 256);            // NG*128
    unsigned* pmax = (unsigned*)(psum + NG * 128);  // NG*128
    int* rank    = (int*)scb;          // aliases scb

    hipMemsetAsync(deg, 0, NN * sizeof(int), stream);
    hipMemsetAsync(stats, 0, 7 * 256 * sizeof(float), stream);
    hipMemsetAsync(psum, 0, NG * 128 * 2 * sizeof(float), stream);  // psum + pmax

    // weight prep (bf16 transposed)
    k_prep<<<12, 256, 0, stream>>>(gWl, gWr, tWq, tWk, tWv, tWs, Wt);

    // CSR by destination (rank-based; k_fill is atomic-free)
    const int S4 = (NE + 3) / 4;
    const int gQuarter = (S4 + 255) / 256;
    k_deg<<<gQuarter, 256, 0, stream>>>(ei, deg, rank);
    k_scan1<<<NB, 256, 0, stream>>>(deg, bsum);
    k_scan2<<<1, 256, 0, stream>>>(bsum, boff, rp);
    k_scan3<<<NB, 256, 0, stream>>>(deg, boff, rp);
    k_fill<<<gQuarter, 256, 0, stream>>>(ei, rp, rank, edg);

    const int gEmb  = (NN + 63) / 64;
    const int gGemm = (NN + 127) / 128;
    const int gStat = (NN + 127) / 128;
    const int gNode = (NN + 3) / 4;
    const int gPool = (NN + 63) / 64;

    // embedding GEMM -> bA; stats0
    k_gemm_emb<<<gEmb, 256, 0, stream>>>(x_in, emb_W, emb_b, bA, NN);
    k_stats<<<gStat, 256, 0, stream>>>(bA, NN, stats);

    // ping-pong feature buffers: residual source alternates x <-> bA
    k_gemm2bn<1, 1, 0, 1><<<gGemm, 256, 0, stream>>>(bA, nullptr, x, stats, emb_g, emb_be,
                                                     Wt + (size_t)0 * 16384, Wt + (size_t)4 * 16384,
                                                     gbl + 0 * 128, gbr + 0 * 128, xlh, xrh, NN);
    k_gat_aggr<<<gNode, 256, 0, stream>>>(xlh, xrh, gatt + 0 * 128, gbias + 0 * 128, rp, edg, bC);
    k_stats<<<gStat, 256, 0, stream>>>(bC, NN, stats + 1 * 256);
    k_gemm2bn<1, 1, 1, 1><<<gGemm, 256, 0, stream>>>(bC, x, bA, stats + 1 * 256, gg + 0 * 128, gbe + 0 * 128,
                                                     Wt + (size_t)1 * 16384, Wt + (size_t)5 * 16384,
                                                     gbl + 1 * 128, gbr + 1 * 128, xlh, xrh, NN);
    k_gat_aggr<<<gNode, 256, 0, stream>>>(xlh, xrh, gatt + 1 * 128, gbias + 1 * 128, rp, edg, bC);
    k_stats<<<gStat, 256, 0, stream>>>(bC, NN, stats + 2 * 256);
    k_gemm2bn<1, 1, 1, 1><<<gGemm, 256, 0, stream>>>(bC, bA, x, stats + 2 * 256, gg + 1 * 128, gbe + 1 * 128,
                                                     Wt + (size_t)2 * 16384, Wt + (size_t)6 * 16384,
                                                     gbl + 2 * 128, gbr + 2 * 128, xlh, xrh, NN);
    k_gat_aggr<<<gNode, 256, 0, stream>>>(xlh, xrh, gatt + 2 * 128, gbias + 2 * 128, rp, edg, bC);
    k_stats<<<gStat, 256, 0, stream>>>(bC, NN, stats + 3 * 256);
    k_gemm2bn<1, 1, 1, 1><<<gGemm, 256, 0, stream>>>(bC, x, bA, stats + 3 * 256, gg + 2 * 128, gbe + 2 * 128,
                                                     Wt + (size_t)3 * 16384, Wt + (size_t)7 * 16384,
                                                     gbl + 3 * 128, gbr + 3 * 128, xlh, xrh, NN);
    k_gat_aggr<<<gNode, 256, 0, stream>>>(xlh, xrh, gatt + 3 * 128, gbias + 3 * 128, rp, edg, bC);
    k_stats<<<gStat, 256, 0, stream>>>(bC, NN, stats + 4 * 256);

    // TransformerConv: Q/K writes x; V/S skips the duplicate xout write (XOUT=0)
    k_gemm2bn<1, 1, 1, 1><<<gGemm, 256, 0, stream>>>(bC, bA, x, stats + 4 * 256, gg + 3 * 128, gbe + 3 * 128,
                                                     Wt + (size_t)8 * 16384, Wt + (size_t)9 * 16384,
                                                     tbq, tbk, xrh, xlh, NN);   // Q, K
    k_gemm2bn<1, 1, 1, 0><<<gGemm, 256, 0, stream>>>(bC, bA, nullptr, stats + 4 * 256, gg + 3 * 128, gbe + 3 * 128,
                                                     Wt + (size_t)10 * 16384, Wt + (size_t)11 * 16384,
                                                     tbv, tbs, vh, sh, NN);     // V, S(skip, fp16)
    k_trans_aggr<<<gNode, 256, 0, stream>>>(xrh, xlh, vh, sh, rp, edg, bC);
    k_stats<<<gStat, 256, 0, stream>>>(bC, NN, stats + 5 * 256);
    k_bn_final<<<1024, 256, 0, stream>>>(bA, bC, x, stats + 5 * 256, tg, tbe);

    // pooling + head
    k_pool_part<<<gPool, 256, 0, stream>>>(bA, batch, psum, pmax);
    k_pool_final<<<NG, 128, 0, stream>>>(psum, pmax, batch, hpool);
    k_head1<<<NG, 128, 0, stream>>>(hpool, oW1, ob1, t1);
    k_stats<<<(NG + 127) / 128, 256, 0, stream>>>(t1, NG, stats + 6 * 256);
    k_head2<<<NG, 64, 0, stream>>>(t1, stats + 6 * 256, og, obe, oW2, ob2, oW3, ob3, out);
}

// Round 18
// 945.763 us; speedup vs baseline: 1.0283x; 1.0283x over previous
//
#include <hip/hip_runtime.h>
#include <hip/hip_fp16.h>

// ---------------- constants ----------------
namespace {
constexpr int NN = 50000;   // nodes
constexpr int NE = 800000;  // edges
constexpr int NG = 256;     // graphs
constexpr int NF = 34;      // in features
constexpr int NL = 4;       // GAT layers
constexpr int NB = (NN + 255) / 256;  // scan blocks = 196
}
#define EPSB 1e-5f
#define LSLOPE 0.2f
#define INV_SQRT_C 0.17677669529663687f  // 1/sqrt(32)

typedef short bf16x8 __attribute__((ext_vector_type(8)));
typedef float f32x4 __attribute__((ext_vector_type(4)));
typedef _Float16 hv2 __attribute__((ext_vector_type(2)));

static __device__ __forceinline__ short f2bf(float f) {
    unsigned int u = __float_as_uint(f);
    u = (u + 0x7fff + ((u >> 16) & 1)) >> 16;  // RNE
    return (short)u;
}
// order-preserving float<->uint for atomicMax; all encodings > 0, so memset-0 = -inf
static __device__ __forceinline__ unsigned fenc(float x) {
    unsigned u = __float_as_uint(x);
    return (u & 0x80000000u) ? ~u : (u | 0x80000000u);
}
static __device__ __forceinline__ float fdec(unsigned u) {
    return __uint_as_float((u & 0x80000000u) ? (u ^ 0x80000000u) : ~u);
}
// v_dot2_f32_f16: c += a.x*b.x + a.y*b.y (fp32 accumulate)
static __device__ __forceinline__ float fdot2(hv2 a, hv2 b, float c) {
    return __builtin_amdgcn_fdot2(a, b, c, false);
}

// ---------------- CSR build: 4 DISJOINT strands/thread (tid<S guard is load-bearing)
__global__ __launch_bounds__(256) void k_deg(const int* __restrict__ ei,
                                             int* __restrict__ deg,
                                             int* __restrict__ rank) {
    int tid = blockIdx.x * 256 + threadIdx.x;
    const int S = (NE + 3) / 4;  // 200000
    if (tid >= S) return;
#pragma unroll
    for (int k = 0; k < 4; ++k) {
        int e = tid + k * S;
        if (e < NE) rank[e] = atomicAdd(&deg[ei[NE + e]], 1);
    }
}

__global__ __launch_bounds__(256) void k_scan1(const int* __restrict__ deg, int* __restrict__ bsum) {
    __shared__ int sm[256];
    int i = blockIdx.x * 256 + threadIdx.x;
    sm[threadIdx.x] = (i < NN) ? deg[i] : 0;
    __syncthreads();
    for (int off = 128; off > 0; off >>= 1) {
        if (threadIdx.x < off) sm[threadIdx.x] += sm[threadIdx.x + off];
        __syncthreads();
    }
    if (threadIdx.x == 0) bsum[blockIdx.x] = sm[0];
}

__global__ __launch_bounds__(256) void k_scan2(const int* __restrict__ bsum,
                                               int* __restrict__ boff, int* __restrict__ rp) {
    __shared__ int sm[256];
    int t = threadIdx.x;
    int v = (t < NB) ? bsum[t] : 0;
    sm[t] = v;
    __syncthreads();
    for (int off = 1; off < 256; off <<= 1) {
        int u = (t >= off) ? sm[t - off] : 0;
        __syncthreads();
        sm[t] += u;
        __syncthreads();
    }
    if (t < NB) boff[t] = sm[t] - v;
    if (t == 255) rp[NN] = sm[255];
}

__global__ __launch_bounds__(256) void k_scan3(const int* __restrict__ deg,
                                               const int* __restrict__ boff,
                                               int* __restrict__ rp) {
    __shared__ int sm[256];
    int i = blockIdx.x * 256 + threadIdx.x;
    int t = threadIdx.x;
    int v = (i < NN) ? deg[i] : 0;
    sm[t] = v;
    __syncthreads();
    for (int off = 1; off < 256; off <<= 1) {
        int u = (t >= off) ? sm[t - off] : 0;
        __syncthreads();
        sm[t] += u;
        __syncthreads();
    }
    if (i < NN) rp[i] = boff[blockIdx.x] + sm[t] - v;
}

// atomic-free scatter: p = rp[d] + rank[e]; 4 disjoint strands per thread
__global__ __launch_bounds__(256) void k_fill(const int* __restrict__ ei,
                                              const int* __restrict__ rp,
                                              const int* __restrict__ rank,
                                              int2* __restrict__ edg) {
    int tid = blockIdx.x * 256 + threadIdx.x;
    const int S = (NE + 3) / 4;
    if (tid >= S) return;
#pragma unroll
    for (int k = 0; k < 4; ++k) {
        int e = tid + k * S;
        if (e < NE) {
            int s = ei[e];
            int d = ei[NE + e];
            int p = rp[d] + rank[e];
            edg[p] = make_int2(s, d);
        }
    }
}

// ---------------- weight prep: 12x (128,128) fp32 -> transposed bf16 ----------------
__global__ __launch_bounds__(256) void k_prep(const float* __restrict__ gWl,
                                              const float* __restrict__ gWr,
                                              const float* __restrict__ tWq,
                                              const float* __restrict__ tWk,
                                              const float* __restrict__ tWv,
                                              const float* __restrict__ tWs,
                                              short* __restrict__ dst) {
    int m = blockIdx.x;
    const float* src;
    if (m < 4) src = gWl + m * 16384;
    else if (m < 8) src = gWr + (m - 4) * 16384;
    else if (m == 8) src = tWq;
    else if (m == 9) src = tWk;
    else if (m == 10) src = tWv;
    else src = tWs;
    short* d = dst + m * 16384;
    for (int i = threadIdx.x; i < 16384; i += 256) {
        int n = i >> 7, k = i & 127;
        d[i] = f2bf(src[k * 128 + n]);  // Wt[n][k] = W[k][n]
    }
}

// ------- pair-fused MFMA GEMM with FUSED BN(+ReLU)+residual in the A-stage ----------
// XOUT=0 skips the fp32 feature write (for the duplicate V/S consumer).
template <int OUTH0, int OUTH1, int RES, int XOUT>
__global__ __launch_bounds__(256) void k_gemm2bn(const float* __restrict__ src,
                                                 const float* __restrict__ res,
                                                 float* __restrict__ xout,
                                                 const float* __restrict__ st,
                                                 const float* __restrict__ g,
                                                 const float* __restrict__ b,
                                                 const short* __restrict__ Wt0,
                                                 const short* __restrict__ Wt1,
                                                 const float* __restrict__ bias0,
                                                 const float* __restrict__ bias1,
                                                 void* __restrict__ out0,
                                                 void* __restrict__ out1, int nRows) {
    __shared__ short As[128 * 136];
    __shared__ short Bs[128 * 136];
    __shared__ float scsh[256];
    const float invn = 1.f / NN;
    if (threadIdx.x < 128) {
        int c = threadIdx.x;
        float mean = st[c] * invn;
        float var = fmaxf(st[128 + c] * invn - mean * mean, 0.f);
        float s = g[c] * rsqrtf(var + EPSB);
        scsh[c] = s;
        scsh[128 + c] = b[c] - mean * s;
    }
    {
        const int4* Wt4 = (const int4*)Wt0;
        for (int idx = threadIdx.x; idx < 2048; idx += 256) {
            int row = idx >> 4, c8 = idx & 15;
            *(int4*)&Bs[row * 136 + c8 * 8] = Wt4[idx];
        }
    }
    __syncthreads();  // scsh ready
    int r0 = blockIdx.x * 128;
    int rows = nRows - r0; if (rows > 128) rows = 128;
    for (int idx = threadIdx.x; idx < 2048; idx += 256) {
        int r = idx >> 4, c8 = idx & 15;
        short4 sa = {0, 0, 0, 0}, sb = {0, 0, 0, 0};
        if (r < rows) {
            size_t base = (size_t)(r0 + r) * 128 + c8 * 8;
            float4 v0 = *(const float4*)&src[base];
            float4 v1 = *(const float4*)&src[base + 4];
            int c = c8 * 8;
            v0.x = fmaxf(v0.x * scsh[c + 0] + scsh[128 + c + 0], 0.f);
            v0.y = fmaxf(v0.y * scsh[c + 1] + scsh[128 + c + 1], 0.f);
            v0.z = fmaxf(v0.z * scsh[c + 2] + scsh[128 + c + 2], 0.f);
            v0.w = fmaxf(v0.w * scsh[c + 3] + scsh[128 + c + 3], 0.f);
            v1.x = fmaxf(v1.x * scsh[c + 4] + scsh[128 + c + 4], 0.f);
            v1.y = fmaxf(v1.y * scsh[c + 5] + scsh[128 + c + 5], 0.f);
            v1.z = fmaxf(v1.z * scsh[c + 6] + scsh[128 + c + 6], 0.f);
            v1.w = fmaxf(v1.w * scsh[c + 7] + scsh[128 + c + 7], 0.f);
            if (RES) {
                float4 rr0 = *(const float4*)&res[base];
                float4 rr1 = *(const float4*)&res[base + 4];
                v0.x += rr0.x; v0.y += rr0.y; v0.z += rr0.z; v0.w += rr0.w;
                v1.x += rr1.x; v1.y += rr1.y; v1.z += rr1.z; v1.w += rr1.w;
            }
            if (XOUT) {
                *(float4*)&xout[base] = v0;
                *(float4*)&xout[base + 4] = v1;
            }
            sa.x = f2bf(v0.x); sa.y = f2bf(v0.y); sa.z = f2bf(v0.z); sa.w = f2bf(v0.w);
            sb.x = f2bf(v1.x); sb.y = f2bf(v1.y); sb.z = f2bf(v1.z); sb.w = f2bf(v1.w);
        }
        *(short4*)&As[r * 136 + c8 * 8] = sa;
        *(short4*)&As[r * 136 + c8 * 8 + 4] = sb;
    }
    __syncthreads();
    int lane = threadIdx.x & 63, wave = threadIdx.x >> 6;
    int n16 = lane & 15, quad = lane >> 4;
    bf16x8 af[2][4];
#pragma unroll
    for (int rt = 0; rt < 2; ++rt)
#pragma unroll
        for (int kc = 0; kc < 4; ++kc)
            af[rt][kc] = *(const bf16x8*)&As[(wave * 32 + rt * 16 + n16) * 136 + kc * 32 + quad * 8];

    f32x4 acc[2][8];
#pragma unroll
    for (int rt = 0; rt < 2; ++rt)
#pragma unroll
        for (int ct = 0; ct < 8; ++ct) acc[rt][ct] = (f32x4){0.f, 0.f, 0.f, 0.f};
#pragma unroll
    for (int ct = 0; ct < 8; ++ct)
#pragma unroll
        for (int kc = 0; kc < 4; ++kc) {
            bf16x8 bf = *(const bf16x8*)&Bs[(ct * 16 + n16) * 136 + kc * 32 + quad * 8];
            acc[0][ct] = __builtin_amdgcn_mfma_f32_16x16x32_bf16(af[0][kc], bf, acc[0][ct], 0, 0, 0);
            acc[1][ct] = __builtin_amdgcn_mfma_f32_16x16x32_bf16(af[1][kc], bf, acc[1][ct], 0, 0, 0);
        }
#pragma unroll
    for (int ct = 0; ct < 8; ++ct) {
        int colI = ct * 16 + n16;
        float bv = bias0[colI];
#pragma unroll
        for (int rt = 0; rt < 2; ++rt)
#pragma unroll
            for (int reg = 0; reg < 4; ++reg) {
                int r = wave * 32 + rt * 16 + quad * 4 + reg;  // C/D: col=lane&15, row=quad*4+reg
                if (r < rows) {
                    float v = acc[rt][ct][reg] + bv;
                    if (OUTH0) ((__half*)out0)[(size_t)(r0 + r) * 128 + colI] = __float2half(v);
                    else       ((float*)out0)[(size_t)(r0 + r) * 128 + colI] = v;
                }
            }
    }
    __syncthreads();
    {
        const int4* Wt4 = (const int4*)Wt1;
        for (int idx = threadIdx.x; idx < 2048; idx += 256) {
            int row = idx >> 4, c8 = idx & 15;
            *(int4*)&Bs[row * 136 + c8 * 8] = Wt4[idx];
        }
    }
    __syncthreads();
#pragma unroll
    for (int rt = 0; rt < 2; ++rt)
#pragma unroll
        for (int ct = 0; ct < 8; ++ct) acc[rt][ct] = (f32x4){0.f, 0.f, 0.f, 0.f};
#pragma unroll
    for (int ct = 0; ct < 8; ++ct)
#pragma unroll
        for (int kc = 0; kc < 4; ++kc) {
            bf16x8 bf = *(const bf16x8*)&Bs[(ct * 16 + n16) * 136 + kc * 32 + quad * 8];
            acc[0][ct] = __builtin_amdgcn_mfma_f32_16x16x32_bf16(af[0][kc], bf, acc[0][ct], 0, 0, 0);
            acc[1][ct] = __builtin_amdgcn_mfma_f32_16x16x32_bf16(af[1][kc], bf, acc[1][ct], 0, 0, 0);
        }
#pragma unroll
    for (int ct = 0; ct < 8; ++ct) {
        int colI = ct * 16 + n16;
        float bv = bias1[colI];
#pragma unroll
        for (int rt = 0; rt < 2; ++rt)
#pragma unroll
            for (int reg = 0; reg < 4; ++reg) {
                int r = wave * 32 + rt * 16 + quad * 4 + reg;
                if (r < rows) {
                    float v = acc[rt][ct][reg] + bv;
                    if (OUTH1) ((__half*)out1)[(size_t)(r0 + r) * 128 + colI] = __float2half(v);
                    else       ((float*)out1)[(size_t)(r0 + r) * 128 + colI] = v;
                }
            }
    }
}

// ---------------- GEMM: (n,34) @ (34,128) + bias (fp32 VALU) ----------
__global__ __launch_bounds__(256) void k_gemm_emb(const float* __restrict__ A,
                                                  const float* __restrict__ W,
                                                  const float* __restrict__ bias,
                                                  float* __restrict__ out, int nRows) {
    __shared__ float As[64 * NF];
    int r0 = blockIdx.x * 64;
    int rows = nRows - r0; if (rows > 64) rows = 64;
    int total = rows * NF;
    for (int idx = threadIdx.x; idx < 64 * NF; idx += 256)
        As[idx] = (idx < total) ? A[(size_t)r0 * NF + idx] : 0.f;
    __syncthreads();
    int tx = threadIdx.x & 31, ty = threadIdx.x >> 5;
    const float4* W4 = (const float4*)W;
    float acc[8][4];
#pragma unroll
    for (int j = 0; j < 8; ++j)
#pragma unroll
        for (int i = 0; i < 4; ++i) acc[j][i] = 0.f;
#pragma unroll 2
    for (int k = 0; k < NF; ++k) {
        float4 w = W4[k * 32 + tx];
#pragma unroll
        for (int j = 0; j < 8; ++j) {
            float a = As[(ty * 8 + j) * NF + k];
            acc[j][0] += a * w.x; acc[j][1] += a * w.y;
            acc[j][2] += a * w.z; acc[j][3] += a * w.w;
        }
    }
    float4 b = ((const float4*)bias)[tx];
#pragma unroll
    for (int j = 0; j < 8; ++j) {
        int r = ty * 8 + j;
        if (r < rows) {
            float4 o = make_float4(acc[j][0] + b.x, acc[j][1] + b.y,
                                   acc[j][2] + b.z, acc[j][3] + b.w);
            ((float4*)out)[(size_t)(r0 + r) * 32 + tx] = o;
        }
    }
}

// ---------------- BN statistics (per-column sum / sumsq) ----------------
__global__ __launch_bounds__(256) void k_stats(const float* __restrict__ src, int nRows,
                                               float* __restrict__ st) {
    int c = threadIdx.x & 127;
    int sub = threadIdx.x >> 7;  // 0/1
    int r0 = blockIdx.x * 128;
    int rend = r0 + 128; if (rend > nRows) rend = nRows;
    float s = 0.f, ss = 0.f;
    for (int r = r0 + sub; r < rend; r += 2) {
        float v = src[(size_t)r * 128 + c];
        s += v; ss += v * v;
    }
    atomicAdd(&st[c], s);
    atomicAdd(&st[128 + c], ss);
}

// final (non-ReLU) BN: dst = res + bn(src)
__global__ __launch_bounds__(256) void k_bn_final(float* __restrict__ dst,
                                                  const float* __restrict__ src,
                                                  const float* __restrict__ res,
                                                  const float* __restrict__ st,
                                                  const float* __restrict__ g,
                                                  const float* __restrict__ b) {
    int tid = blockIdx.x * blockDim.x + threadIdx.x;
    int cb = (tid & 31) * 4;
    const float invn = 1.f / NN;
    float sc[4], sh[4];
#pragma unroll
    for (int k = 0; k < 4; ++k) {
        float mean = st[cb + k] * invn;
        float var = fmaxf(st[128 + cb + k] * invn - mean * mean, 0.f);
        float s = g[cb + k] * rsqrtf(var + EPSB);
        sc[k] = s; sh[k] = b[cb + k] - mean * s;
    }
    const float4* s4 = (const float4*)src;
    const float4* r4 = (const float4*)res;
    float4* d4 = (float4*)dst;
    const int total = NN * 32;
    for (int i = tid; i < total; i += gridDim.x * blockDim.x) {
        float4 v = s4[i];
        float4 rr = r4[i];
        v.x = v.x * sc[0] + sh[0] + rr.x;
        v.y = v.y * sc[1] + sh[1] + rr.y;
        v.z = v.z * sc[2] + sh[2] + rr.z;
        v.w = v.w * sc[3] + sh[3] + rr.w;
        d4[i] = v;
    }
}

// ---- FUSED GAT edge pass: quarter-wave per edge (16 lanes x 8 chans), fp16 score ----
// head = l16>>2 (4 lanes/head, 32 chans); dot reduction = 2 shfl_xor (1,2).
// 4 edges in flight per wave instruction stream; 16B gathers.
__global__ __launch_bounds__(256) void k_gat_aggr(const __half* __restrict__ xl,
                                                  const __half* __restrict__ xr,
                                                  const float* __restrict__ att,
                                                  const float* __restrict__ gbias_l,
                                                  const int* __restrict__ rp,
                                                  const int2* __restrict__ edg,
                                                  float* __restrict__ out) {
    int lane = threadIdx.x & 63;
    int node = blockIdx.x * 4 + (threadIdx.x >> 6);
    if (node >= NN) return;
    int q = lane >> 4;      // edge strand 0..3
    int l16 = lane & 15;
    int c8 = l16 * 8;
    // preload xr[node] (8 chans) and att (8 chans) as packed half2
    float4 xrr = *(const float4*)&xr[(unsigned)node * 128u + c8];
    hv2 xrh[4] = {*(hv2*)&xrr.x, *(hv2*)&xrr.y, *(hv2*)&xrr.z, *(hv2*)&xrr.w};
    float4 atA = *(const float4*)&att[c8];
    float4 atB = *(const float4*)&att[c8 + 4];
    hv2 ath[4] = {{(_Float16)atA.x, (_Float16)atA.y}, {(_Float16)atA.z, (_Float16)atA.w},
                  {(_Float16)atB.x, (_Float16)atB.y}, {(_Float16)atB.z, (_Float16)atB.w}};
    const hv2 hz = {(_Float16)0.f, (_Float16)0.f};
    const hv2 hs = {(_Float16)LSLOPE, (_Float16)LSLOPE};
    int s0 = rp[node];
    int T = rp[node + 1] - s0 + 1;  // logical edge T-1 is the self loop
    float a[8] = {0.f, 0.f, 0.f, 0.f, 0.f, 0.f, 0.f, 0.f};
    float l = 0.f;
    auto body = [&](int j) {
        bool self = (j == T - 1);
        int src = self ? node : edg[s0 + j].x;
        float4 raw = *(const float4*)&xl[(unsigned)src * 128u + c8];
        hv2 f[4] = {*(hv2*)&raw.x, *(hv2*)&raw.y, *(hv2*)&raw.z, *(hv2*)&raw.w};
        float p = 0.f;
#pragma unroll
        for (int k = 0; k < 4; ++k) {
            hv2 e = f[k] + xrh[k];
            hv2 lk = __builtin_elementwise_max(e, hz) + hs * __builtin_elementwise_min(e, hz);
            p = fdot2(lk, ath[k], p);
        }
        p += __shfl_xor(p, 1); p += __shfl_xor(p, 2);
        float w = __expf(p);
#pragma unroll
        for (int k = 0; k < 4; ++k) {
            a[2 * k] += w * (float)f[k].x;
            a[2 * k + 1] += w * (float)f[k].y;
        }
        l += w;
    };
    int j = q;
    for (; j + 4 < T; j += 8) { body(j); body(j + 4); }
    for (; j < T; j += 4) body(j);
#pragma unroll
    for (int k = 0; k < 8; ++k) { a[k] += __shfl_xor(a[k], 16); a[k] += __shfl_xor(a[k], 32); }
    l += __shfl_xor(l, 16); l += __shfl_xor(l, 32);
    if (q == 0) {
        float inv = 1.f / (l + 1e-16f);
        float4 gb0 = *(const float4*)&gbias_l[c8];
        float4 gb1 = *(const float4*)&gbias_l[c8 + 4];
        float4 o0 = make_float4(a[0] * inv + gb0.x, a[1] * inv + gb0.y,
                                a[2] * inv + gb0.z, a[3] * inv + gb0.w);
        float4 o1 = make_float4(a[4] * inv + gb1.x, a[5] * inv + gb1.y,
                                a[6] * inv + gb1.z, a[7] * inv + gb1.w);
        *(float4*)&out[(unsigned)node * 128u + c8] = o0;
        *(float4*)&out[(unsigned)node * 128u + c8 + 4] = o1;
    }
}

// ---- FUSED Transformer edge pass: quarter-wave per edge, fdot2 QK, fp16 skip -------
__global__ __launch_bounds__(256) void k_trans_aggr(const __half* __restrict__ qh,
                                                    const __half* __restrict__ kh,
                                                    const __half* __restrict__ vv,
                                                    const __half* __restrict__ sT,
                                                    const int* __restrict__ rp,
                                                    const int2* __restrict__ edg,
                                                    float* __restrict__ out) {
    int lane = threadIdx.x & 63;
    int node = blockIdx.x * 4 + (threadIdx.x >> 6);
    if (node >= NN) return;
    int q = lane >> 4;
    int l16 = lane & 15;
    int c8 = l16 * 8;
    float4 qr = *(const float4*)&qh[(unsigned)node * 128u + c8];
    const hv2 hinv = {(_Float16)INV_SQRT_C, (_Float16)INV_SQRT_C};
    hv2 qv[4] = {(*(hv2*)&qr.x) * hinv, (*(hv2*)&qr.y) * hinv,
                 (*(hv2*)&qr.z) * hinv, (*(hv2*)&qr.w) * hinv};
    int s0 = rp[node];
    int T = rp[node + 1] - s0;
    float a[8] = {0.f, 0.f, 0.f, 0.f, 0.f, 0.f, 0.f, 0.f};
    float l = 0.f;
    auto body = [&](int j) {
        int src = edg[s0 + j].x;
        float4 kraw = *(const float4*)&kh[(unsigned)src * 128u + c8];
        float4 vraw = *(const float4*)&vv[(unsigned)src * 128u + c8];
        hv2 kv[4] = {*(hv2*)&kraw.x, *(hv2*)&kraw.y, *(hv2*)&kraw.z, *(hv2*)&kraw.w};
        float p = 0.f;
#pragma unroll
        for (int k = 0; k < 4; ++k) p = fdot2(kv[k], qv[k], p);
        p += __shfl_xor(p, 1); p += __shfl_xor(p, 2);
        float w = __expf(p);
        hv2 vvv[4] = {*(hv2*)&vraw.x, *(hv2*)&vraw.y, *(hv2*)&vraw.z, *(hv2*)&vraw.w};
#pragma unroll
        for (int k = 0; k < 4; ++k) {
            a[2 * k] += w * (float)vvv[k].x;
            a[2 * k + 1] += w * (float)vvv[k].y;
        }
        l += w;
    };
    int j = q;
    for (; j + 4 < T; j += 8) { body(j); body(j + 4); }
    for (; j < T; j += 4) body(j);
#pragma unroll
    for (int k = 0; k < 8; ++k) { a[k] += __shfl_xor(a[k], 16); a[k] += __shfl_xor(a[k], 32); }
    l += __shfl_xor(l, 16); l += __shfl_xor(l, 32);
    if (q == 0) {
        float inv = 1.f / (l + 1e-16f);
        float4 straw = *(const float4*)&sT[(unsigned)node * 128u + c8];
        hv2 st[4] = {*(hv2*)&straw.x, *(hv2*)&straw.y, *(hv2*)&straw.z, *(hv2*)&straw.w};
        float4 o0 = make_float4(a[0] * inv + (float)st[0].x, a[1] * inv + (float)st[0].y,
                                a[2] * inv + (float)st[1].x, a[3] * inv + (float)st[1].y);
        float4 o1 = make_float4(a[4] * inv + (float)st[2].x, a[5] * inv + (float)st[2].y,
                                a[6] * inv + (float)st[3].x, a[7] * inv + (float)st[3].y);
        *(float4*)&out[(unsigned)node * 128u + c8] = o0;
        *(float4*)&out[(unsigned)node * 128u + c8 + 4] = o1;
    }
}

// ---------------- pooling phase 1: node-parallel partials (batch sorted) ------------
__global__ __launch_bounds__(256) void k_pool_part(const float* __restrict__ x,
                                                   const int* __restrict__ batch,
                                                   float* __restrict__ psum,
                                                   unsigned* __restrict__ pmax) {
    __shared__ int bs[64];
    int r0 = blockIdx.x * 64;
    if (threadIdx.x < 64) {
        int r = r0 + threadIdx.x;
        bs[threadIdx.x] = (r < NN) ? batch[r] : -1;
    }
    __syncthreads();
    int c = threadIdx.x & 127;
    int sub = threadIdx.x >> 7;
    int curg = -1;
    float s = 0.f, fmx = -INFINITY;
    for (int i = sub; i < 64; i += 2) {
        int r = r0 + i;
        if (r >= NN) break;
        int g = bs[i];
        if (g != curg) {
            if (curg >= 0) {
                atomicAdd(&psum[curg * 128 + c], s);
                atomicMax(&pmax[curg * 128 + c], fenc(fmx));
            }
            curg = g; s = 0.f; fmx = -INFINITY;
        }
        float v = x[(size_t)r * 128 + c];
        s += v; fmx = fmaxf(fmx, v);
    }
    if (curg >= 0) {
        atomicAdd(&psum[curg * 128 + c], s);
        atomicMax(&pmax[curg * 128 + c], fenc(fmx));
    }
}

// ---------------- pooling phase 2: finalize ----------------
__global__ __launch_bounds__(128) void k_pool_final(const float* __restrict__ psum,
                                                    const unsigned* __restrict__ pmax,
                                                    const int* __restrict__ batch,
                                                    float* __restrict__ h) {
    __shared__ int se[2];
    int g = blockIdx.x;
    if (threadIdx.x == 0) {
        int lo = 0, hi = NN;
        while (lo < hi) { int mid = (lo + hi) >> 1; if (batch[mid] < g) lo = mid + 1; else hi = mid; }
        se[0] = lo;
        hi = NN;
        while (lo < hi) { int mid = (lo + hi) >> 1; if (batch[mid] < g + 1) lo = mid + 1; else hi = mid; }
        se[1] = lo;
    }
    __syncthreads();
    int cnt = se[1] - se[0];
    int c = threadIdx.x;
    float xm = psum[g * 128 + c] / fmaxf((float)cnt, 1.f);
    float xx = (cnt > 0) ? fdec(pmax[g * 128 + c]) : 0.f;
    h[g * 256 + c] = xm;
    h[g * 256 + 128 + c] = xx;
}

// ---------------- head ----------------
__global__ __launch_bounds__(128) void k_head1(const float* __restrict__ h,
                                               const float* __restrict__ W,
                                               const float* __restrict__ b,
                                               float* __restrict__ t1) {
    __shared__ float hr[256];
    int row = blockIdx.x;
    int t = threadIdx.x;
    hr[t] = h[row * 256 + t];
    hr[t + 128] = h[row * 256 + 128 + t];
    __syncthreads();
    float acc = b[t];
#pragma unroll 4
    for (int k = 0; k < 256; ++k) acc += hr[k] * W[k * 128 + t];
    t1[row * 128 + t] = acc;
}

__global__ __launch_bounds__(64) void k_head2(const float* __restrict__ t1,
                                              const float* __restrict__ st,
                                              const float* __restrict__ og,
                                              const float* __restrict__ obe,
                                              const float* __restrict__ W2,
                                              const float* __restrict__ b2,
                                              const float* __restrict__ W3,
                                              const float* __restrict__ b3,
                                              float* __restrict__ out) {
    __shared__ float v[128];
    int row = blockIdx.x, t = threadIdx.x;
    const float invn = 1.f / NG;
#pragma unroll
    for (int half = 0; half < 2; ++half) {
        int ch = t + half * 64;
        float mean = st[ch] * invn;
        float var = fmaxf(st[128 + ch] * invn - mean * mean, 0.f);
        float scv = og[ch] * rsqrtf(var + EPSB);
        float shv = obe[ch] - mean * scv;
        float a = t1[row * 128 + ch] * scv + shv;
        v[ch] = fmaxf(a, 0.f);
    }
    __syncthreads();
    float acc = b2[t];
#pragma unroll 4
    for (int k = 0; k < 128; ++k) acc += v[k] * W2[k * 64 + t];
    float p = fmaxf(acc, 0.f) * W3[t];
    p += __shfl_xor(p, 1); p += __shfl_xor(p, 2); p += __shfl_xor(p, 4);
    p += __shfl_xor(p, 8); p += __shfl_xor(p, 16); p += __shfl_xor(p, 32);
    if (t == 0) out[row] = p + b3[0];
}

// ---------------- launch ----------------
extern "C" void kernel_launch(void* const* d_in, const int* in_sizes, int n_in,
                              void* d_out, int out_size, void* d_ws, size_t ws_size,
                              hipStream_t stream) {
    const float* x_in   = (const float*)d_in[0];
    const int*   ei     = (const int*)d_in[1];
    const int*   batch  = (const int*)d_in[2];
    const float* emb_W  = (const float*)d_in[3];
    const float* emb_b  = (const float*)d_in[4];
    const float* emb_g  = (const float*)d_in[5];
    const float* emb_be = (const float*)d_in[6];
    const float* gWl    = (const float*)d_in[7];
    const float* gWr    = (const float*)d_in[8];
    const float* gbl    = (const float*)d_in[9];
    const float* gbr    = (const float*)d_in[10];
    const float* gatt   = (const float*)d_in[11];
    const float* gbias  = (const float*)d_in[12];
    const float* gg     = (const float*)d_in[13];
    const float* gbe    = (const float*)d_in[14];
    const float* tWq    = (const float*)d_in[15];
    const float* tWk    = (const float*)d_in[16];
    const float* tWv    = (const float*)d_in[17];
    const float* tWs    = (const float*)d_in[18];
    const float* tbq    = (const float*)d_in[19];
    const float* tbk    = (const float*)d_in[20];
    const float* tbv    = (const float*)d_in[21];
    const float* tbs    = (const float*)d_in[22];
    const float* tg     = (const float*)d_in[23];
    const float* tbe    = (const float*)d_in[24];
    const float* oW1    = (const float*)d_in[25];
    const float* ob1    = (const float*)d_in[26];
    const float* og     = (const float*)d_in[27];
    const float* obe    = (const float*)d_in[28];
    const float* oW2    = (const float*)d_in[29];
    const float* ob2    = (const float*)d_in[30];
    const float* oW3    = (const float*)d_in[31];
    const float* ob3    = (const float*)d_in[32];
    float* out = (float*)d_out;

    const size_t NDsz = (size_t)NN * 128;
    float* x     = (float*)d_ws;       // ping
    float* bA    = x + NDsz;           // pong (also emb out, final pooled input)
    float* bC    = bA + NDsz;          // aggr output / pre-BN
    float* stats = bC + NDsz;          // 7 * 256 floats
    float* hpool = stats + 7 * 256;    // 256*256
    float* t1    = hpool + 65536;      // 256*128
    float* scb   = t1 + 32768;         // hosts rank (NE ints)
    __half* xlh  = (__half*)(scb + (size_t)(NE + NN) * 4);  // xl / K
    __half* xrh  = xlh + NDsz;         // xr / Q
    __half* vh   = xrh + NDsz;         // V
    __half* sh   = vh + NDsz;          // S skip (fp16)
    short* Wt    = (short*)(sh + NDsz);  // 12 * 128*128 bf16 transposed
    int* deg     = (int*)(Wt + 12 * 16384);
    int* rp      = deg + NN;
    int* cursor  = rp + NN + 1;        // kept (dead) to preserve proven layout
    int2* edg    = (int2*)(cursor + NN);  // NE+64 packed (src,dst)
    int* bsum    = (int*)(edg + NE + 64);
    int* boff    = bsum + 256;
    float* psum  = (float*)(boff + 256);            // NG*128
    unsigned* pmax = (unsigned*)(psum + NG * 128);  // NG*128
    int* rank    = (int*)scb;          // aliases scb

    hipMemsetAsync(deg, 0, NN * sizeof(int), stream);
    hipMemsetAsync(stats, 0, 7 * 256 * sizeof(float), stream);
    hipMemsetAsync(psum, 0, NG * 128 * 2 * sizeof(float), stream);  // psum + pmax

    // weight prep (bf16 transposed)
    k_prep<<<12, 256, 0, stream>>>(gWl, gWr, tWq, tWk, tWv, tWs, Wt);

    // CSR by destination (rank-based; k_fill is atomic-free)
    const int S4 = (NE + 3) / 4;
    const int gQuarter = (S4 + 255) / 256;
    k_deg<<<gQuarter, 256, 0, stream>>>(ei, deg, rank);
    k_scan1<<<NB, 256, 0, stream>>>(deg, bsum);
    k_scan2<<<1, 256, 0, stream>>>(bsum, boff, rp);
    k_scan3<<<NB, 256, 0, stream>>>(deg, boff, rp);
    k_fill<<<gQuarter, 256, 0, stream>>>(ei, rp, rank, edg);

    const int gEmb  = (NN + 63) / 64;
    const int gGemm = (NN + 127) / 128;
    const int gStat = (NN + 127) / 128;
    const int gNode = (NN + 3) / 4;
    const int gPool = (NN + 63) / 64;

    // embedding GEMM -> bA; stats0
    k_gemm_emb<<<gEmb, 256, 0, stream>>>(x_in, emb_W, emb_b, bA, NN);
    k_stats<<<gStat, 256, 0, stream>>>(bA, NN, stats);

    // ping-pong feature buffers: residual source alternates x <-> bA
    k_gemm2bn<1, 1, 0, 1><<<gGemm, 256, 0, stream>>>(bA, nullptr, x, stats, emb_g, emb_be,
                                                     Wt + (size_t)0 * 16384, Wt + (size_t)4 * 16384,
                                                     gbl + 0 * 128, gbr + 0 * 128, xlh, xrh, NN);
    k_gat_aggr<<<gNode, 256, 0, stream>>>(xlh, xrh, gatt + 0 * 128, gbias + 0 * 128, rp, edg, bC);
    k_stats<<<gStat, 256, 0, stream>>>(bC, NN, stats + 1 * 256);
    k_gemm2bn<1, 1, 1, 1><<<gGemm, 256, 0, stream>>>(bC, x, bA, stats + 1 * 256, gg + 0 * 128, gbe + 0 * 128,
                                                     Wt + (size_t)1 * 16384, Wt + (size_t)5 * 16384,
                                                     gbl + 1 * 128, gbr + 1 * 128, xlh, xrh, NN);
    k_gat_aggr<<<gNode, 256, 0, stream>>>(xlh, xrh, gatt + 1 * 128, gbias + 1 * 128, rp, edg, bC);
    k_stats<<<gStat, 256, 0, stream>>>(bC, NN, stats + 2 * 256);
    k_gemm2bn<1, 1, 1, 1><<<gGemm, 256, 0, stream>>>(bC, bA, x, stats + 2 * 256, gg + 1 * 128, gbe + 1 * 128,
                                                     Wt + (size_t)2 * 16384, Wt + (size_t)6 * 16384,
                                                     gbl + 2 * 128, gbr + 2 * 128, xlh, xrh, NN);
    k_gat_aggr<<<gNode, 256, 0, stream>>>(xlh, xrh, gatt + 2 * 128, gbias + 2 * 128, rp, edg, bC);
    k_stats<<<gStat, 256, 0, stream>>>(bC, NN, stats + 3 * 256);
    k_gemm2bn<1, 1, 1, 1><<<gGemm, 256, 0, stream>>>(bC, x, bA, stats + 3 * 256, gg + 2 * 128, gbe + 2 * 128,
                                                     Wt + (size_t)3 * 16384, Wt + (size_t)7 * 16384,
                                                     gbl + 3 * 128, gbr + 3 * 128, xlh, xrh, NN);
    k_gat_aggr<<<gNode, 256, 0, stream>>>(xlh, xrh, gatt + 3 * 128, gbias + 3 * 128, rp, edg, bC);
    k_stats<<<gStat, 256, 0, stream>>>(bC, NN, stats + 4 * 256);

    // TransformerConv: Q/K writes x; V/S skips the duplicate xout write (XOUT=0)
    k_gemm2bn<1, 1, 1, 1><<<gGemm, 256, 0, stream>>>(bC, bA, x, stats + 4 * 256, gg + 3 * 128, gbe + 3 * 128,
                                                     Wt + (size_t)8 * 16384, Wt + (size_t)9 * 16384,
                                                     tbq, tbk, xrh, xlh, NN);   // Q, K
    k_gemm2bn<1, 1, 1, 0><<<gGemm, 256, 0, stream>>>(bC, bA, nullptr, stats + 4 * 256, gg + 3 * 128, gbe + 3 * 128,
                                                     Wt + (size_t)10 * 16384, Wt + (size_t)11 * 16384,
                                                     tbv, tbs, vh, sh, NN);     // V, S(skip, fp16)
    k_trans_aggr<<<gNode, 256, 0, stream>>>(xrh, xlh, vh, sh, rp, edg, bC);
    k_stats<<<gStat, 256, 0, stream>>>(bC, NN, stats + 5 * 256);
    k_bn_final<<<1024, 256, 0, stream>>>(bA, bC, x, stats + 5 * 256, tg, tbe);

    // pooling + head
    k_pool_part<<<gPool, 256, 0, stream>>>(bA, batch, psum, pmax);
    k_pool_final<<<NG, 128, 0, stream>>>(psum, pmax, batch, hpool);
    k_head1<<<NG, 128, 0, stream>>>(hpool, oW1, ob1, t1);
    k_stats<<<(NG + 127) / 128, 256, 0, stream>>>(t1, NG, stats + 6 * 256);
    k_head2<<<NG, 64, 0, stream>>>(t1, stats + 6 * 256, og, obe, oW2, ob2, oW3, ob3, out);
}

// Round 19
// 918.751 us; speedup vs baseline: 1.0586x; 1.0294x over previous
//
#include <hip/hip_runtime.h>
#include <hip/hip_fp16.h>

// ---------------- constants ----------------
namespace {
constexpr int NN = 50000;   // nodes
constexpr int NE = 800000;  // edges
constexpr int NG = 256;     // graphs
constexpr int NF = 34;      // in features
constexpr int NL = 4;       // GAT layers
constexpr int NB = (NN + 255) / 256;  // scan blocks = 196
}
#define EPSB 1e-5f
#define LSLOPE 0.2f
#define INV_SQRT_C 0.17677669529663687f  // 1/sqrt(32)

typedef short bf16x8 __attribute__((ext_vector_type(8)));
typedef float f32x4 __attribute__((ext_vector_type(4)));
typedef _Float16 hv2 __attribute__((ext_vector_type(2)));

static __device__ __forceinline__ short f2bf(float f) {
    unsigned int u = __float_as_uint(f);
    u = (u + 0x7fff + ((u >> 16) & 1)) >> 16;  // RNE
    return (short)u;
}
// order-preserving float<->uint for atomicMax; all encodings > 0, so memset-0 = -inf
static __device__ __forceinline__ unsigned fenc(float x) {
    unsigned u = __float_as_uint(x);
    return (u & 0x80000000u) ? ~u : (u | 0x80000000u);
}
static __device__ __forceinline__ float fdec(unsigned u) {
    return __uint_as_float((u & 0x80000000u) ? (u ^ 0x80000000u) : ~u);
}
// v_dot2_f32_f16: c += a.x*b.x + a.y*b.y (fp32 accumulate)
static __device__ __forceinline__ float fdot2(hv2 a, hv2 b, float c) {
    return __builtin_amdgcn_fdot2(a, b, c, false);
}

// ---------------- CSR build: 4 DISJOINT strands/thread (tid<S guard is load-bearing)
__global__ __launch_bounds__(256) void k_deg(const int* __restrict__ ei,
                                             int* __restrict__ deg,
                                             int* __restrict__ rank) {
    int tid = blockIdx.x * 256 + threadIdx.x;
    const int S = (NE + 3) / 4;  // 200000
    if (tid >= S) return;
#pragma unroll
    for (int k = 0; k < 4; ++k) {
        int e = tid + k * S;
        if (e < NE) rank[e] = atomicAdd(&deg[ei[NE + e]], 1);
    }
}

__global__ __launch_bounds__(256) void k_scan1(const int* __restrict__ deg, int* __restrict__ bsum) {
    __shared__ int sm[256];
    int i = blockIdx.x * 256 + threadIdx.x;
    sm[threadIdx.x] = (i < NN) ? deg[i] : 0;
    __syncthreads();
    for (int off = 128; off > 0; off >>= 1) {
        if (threadIdx.x < off) sm[threadIdx.x] += sm[threadIdx.x + off];
        __syncthreads();
    }
    if (threadIdx.x == 0) bsum[blockIdx.x] = sm[0];
}

__global__ __launch_bounds__(256) void k_scan2(const int* __restrict__ bsum,
                                               int* __restrict__ boff, int* __restrict__ rp) {
    __shared__ int sm[256];
    int t = threadIdx.x;
    int v = (t < NB) ? bsum[t] : 0;
    sm[t] = v;
    __syncthreads();
    for (int off = 1; off < 256; off <<= 1) {
        int u = (t >= off) ? sm[t - off] : 0;
        __syncthreads();
        sm[t] += u;
        __syncthreads();
    }
    if (t < NB) boff[t] = sm[t] - v;
    if (t == 255) rp[NN] = sm[255];
}

__global__ __launch_bounds__(256) void k_scan3(const int* __restrict__ deg,
                                               const int* __restrict__ boff,
                                               int* __restrict__ rp) {
    __shared__ int sm[256];
    int i = blockIdx.x * 256 + threadIdx.x;
    int t = threadIdx.x;
    int v = (i < NN) ? deg[i] : 0;
    sm[t] = v;
    __syncthreads();
    for (int off = 1; off < 256; off <<= 1) {
        int u = (t >= off) ? sm[t - off] : 0;
        __syncthreads();
        sm[t] += u;
        __syncthreads();
    }
    if (i < NN) rp[i] = boff[blockIdx.x] + sm[t] - v;
}

// atomic-free scatter: p = rp[d] + rank[e]; 4 disjoint strands per thread
__global__ __launch_bounds__(256) void k_fill(const int* __restrict__ ei,
                                              const int* __restrict__ rp,
                                              const int* __restrict__ rank,
                                              int2* __restrict__ edg) {
    int tid = blockIdx.x * 256 + threadIdx.x;
    const int S = (NE + 3) / 4;
    if (tid >= S) return;
#pragma unroll
    for (int k = 0; k < 4; ++k) {
        int e = tid + k * S;
        if (e < NE) {
            int s = ei[e];
            int d = ei[NE + e];
            int p = rp[d] + rank[e];
            edg[p] = make_int2(s, d);
        }
    }
}

// ---------------- weight prep: 12x (128,128) fp32 -> transposed bf16 ----------------
__global__ __launch_bounds__(256) void k_prep(const float* __restrict__ gWl,
                                              const float* __restrict__ gWr,
                                              const float* __restrict__ tWq,
                                              const float* __restrict__ tWk,
                                              const float* __restrict__ tWv,
                                              const float* __restrict__ tWs,
                                              short* __restrict__ dst) {
    int m = blockIdx.x;
    const float* src;
    if (m < 4) src = gWl + m * 16384;
    else if (m < 8) src = gWr + (m - 4) * 16384;
    else if (m == 8) src = tWq;
    else if (m == 9) src = tWk;
    else if (m == 10) src = tWv;
    else src = tWs;
    short* d = dst + m * 16384;
    for (int i = threadIdx.x; i < 16384; i += 256) {
        int n = i >> 7, k = i & 127;
        d[i] = f2bf(src[k * 128 + n]);  // Wt[n][k] = W[k][n]
    }
}

// ------- pair-fused MFMA GEMM with FUSED BN(+ReLU)+residual in the A-stage ----------
// XOUT=0 skips the fp32 feature write (for the duplicate V/S consumer).
template <int OUTH0, int OUTH1, int RES, int XOUT>
__global__ __launch_bounds__(256) void k_gemm2bn(const float* __restrict__ src,
                                                 const float* __restrict__ res,
                                                 float* __restrict__ xout,
                                                 const float* __restrict__ st,
                                                 const float* __restrict__ g,
                                                 const float* __restrict__ b,
                                                 const short* __restrict__ Wt0,
                                                 const short* __restrict__ Wt1,
                                                 const float* __restrict__ bias0,
                                                 const float* __restrict__ bias1,
                                                 void* __restrict__ out0,
                                                 void* __restrict__ out1, int nRows) {
    __shared__ short As[128 * 136];
    __shared__ short Bs[128 * 136];
    __shared__ float scsh[256];
    const float invn = 1.f / NN;
    if (threadIdx.x < 128) {
        int c = threadIdx.x;
        float mean = st[c] * invn;
        float var = fmaxf(st[128 + c] * invn - mean * mean, 0.f);
        float s = g[c] * rsqrtf(var + EPSB);
        scsh[c] = s;
        scsh[128 + c] = b[c] - mean * s;
    }
    {
        const int4* Wt4 = (const int4*)Wt0;
        for (int idx = threadIdx.x; idx < 2048; idx += 256) {
            int row = idx >> 4, c8 = idx & 15;
            *(int4*)&Bs[row * 136 + c8 * 8] = Wt4[idx];
        }
    }
    __syncthreads();  // scsh ready
    int r0 = blockIdx.x * 128;
    int rows = nRows - r0; if (rows > 128) rows = 128;
    for (int idx = threadIdx.x; idx < 2048; idx += 256) {
        int r = idx >> 4, c8 = idx & 15;
        short4 sa = {0, 0, 0, 0}, sb = {0, 0, 0, 0};
        if (r < rows) {
            size_t base = (size_t)(r0 + r) * 128 + c8 * 8;
            float4 v0 = *(const float4*)&src[base];
            float4 v1 = *(const float4*)&src[base + 4];
            int c = c8 * 8;
            v0.x = fmaxf(v0.x * scsh[c + 0] + scsh[128 + c + 0], 0.f);
            v0.y = fmaxf(v0.y * scsh[c + 1] + scsh[128 + c + 1], 0.f);
            v0.z = fmaxf(v0.z * scsh[c + 2] + scsh[128 + c + 2], 0.f);
            v0.w = fmaxf(v0.w * scsh[c + 3] + scsh[128 + c + 3], 0.f);
            v1.x = fmaxf(v1.x * scsh[c + 4] + scsh[128 + c + 4], 0.f);
            v1.y = fmaxf(v1.y * scsh[c + 5] + scsh[128 + c + 5], 0.f);
            v1.z = fmaxf(v1.z * scsh[c + 6] + scsh[128 + c + 6], 0.f);
            v1.w = fmaxf(v1.w * scsh[c + 7] + scsh[128 + c + 7], 0.f);
            if (RES) {
                float4 rr0 = *(const float4*)&res[base];
                float4 rr1 = *(const float4*)&res[base + 4];
                v0.x += rr0.x; v0.y += rr0.y; v0.z += rr0.z; v0.w += rr0.w;
                v1.x += rr1.x; v1.y += rr1.y; v1.z += rr1.z; v1.w += rr1.w;
            }
            if (XOUT) {
                *(float4*)&xout[base] = v0;
                *(float4*)&xout[base + 4] = v1;
            }
            sa.x = f2bf(v0.x); sa.y = f2bf(v0.y); sa.z = f2bf(v0.z); sa.w = f2bf(v0.w);
            sb.x = f2bf(v1.x); sb.y = f2bf(v1.y); sb.z = f2bf(v1.z); sb.w = f2bf(v1.w);
        }
        *(short4*)&As[r * 136 + c8 * 8] = sa;
        *(short4*)&As[r * 136 + c8 * 8 + 4] = sb;
    }
    __syncthreads();
    int lane = threadIdx.x & 63, wave = threadIdx.x >> 6;
    int n16 = lane & 15, quad = lane >> 4;
    bf16x8 af[2][4];
#pragma unroll
    for (int rt = 0; rt < 2; ++rt)
#pragma unroll
        for (int kc = 0; kc < 4; ++kc)
            af[rt][kc] = *(const bf16x8*)&As[(wave * 32 + rt * 16 + n16) * 136 + kc * 32 + quad * 8];

    f32x4 acc[2][8];
#pragma unroll
    for (int rt = 0; rt < 2; ++rt)
#pragma unroll
        for (int ct = 0; ct < 8; ++ct) acc[rt][ct] = (f32x4){0.f, 0.f, 0.f, 0.f};
#pragma unroll
    for (int ct = 0; ct < 8; ++ct)
#pragma unroll
        for (int kc = 0; kc < 4; ++kc) {
            bf16x8 bf = *(const bf16x8*)&Bs[(ct * 16 + n16) * 136 + kc * 32 + quad * 8];
            acc[0][ct] = __builtin_amdgcn_mfma_f32_16x16x32_bf16(af[0][kc], bf, acc[0][ct], 0, 0, 0);
            acc[1][ct] = __builtin_amdgcn_mfma_f32_16x16x32_bf16(af[1][kc], bf, acc[1][ct], 0, 0, 0);
        }
#pragma unroll
    for (int ct = 0; ct < 8; ++ct) {
        int colI = ct * 16 + n16;
        float bv = bias0[colI];
#pragma unroll
        for (int rt = 0; rt < 2; ++rt)
#pragma unroll
            for (int reg = 0; reg < 4; ++reg) {
                int r = wave * 32 + rt * 16 + quad * 4 + reg;  // C/D: col=lane&15, row=quad*4+reg
                if (r < rows) {
                    float v = acc[rt][ct][reg] + bv;
                    if (OUTH0) ((__half*)out0)[(size_t)(r0 + r) * 128 + colI] = __float2half(v);
                    else       ((float*)out0)[(size_t)(r0 + r) * 128 + colI] = v;
                }
            }
    }
    __syncthreads();
    {
        const int4* Wt4 = (const int4*)Wt1;
        for (int idx = threadIdx.x; idx < 2048; idx += 256) {
            int row = idx >> 4, c8 = idx & 15;
            *(int4*)&Bs[row * 136 + c8 * 8] = Wt4[idx];
        }
    }
    __syncthreads();
#pragma unroll
    for (int rt = 0; rt < 2; ++rt)
#pragma unroll
        for (int ct = 0; ct < 8; ++ct) acc[rt][ct] = (f32x4){0.f, 0.f, 0.f, 0.f};
#pragma unroll
    for (int ct = 0; ct < 8; ++ct)
#pragma unroll
        for (int kc = 0; kc < 4; ++kc) {
            bf16x8 bf = *(const bf16x8*)&Bs[(ct * 16 + n16) * 136 + kc * 32 + quad * 8];
            acc[0][ct] = __builtin_amdgcn_mfma_f32_16x16x32_bf16(af[0][kc], bf, acc[0][ct], 0, 0, 0);
            acc[1][ct] = __builtin_amdgcn_mfma_f32_16x16x32_bf16(af[1][kc], bf, acc[1][ct], 0, 0, 0);
        }
#pragma unroll
    for (int ct = 0; ct < 8; ++ct) {
        int colI = ct * 16 + n16;
        float bv = bias1[colI];
#pragma unroll
        for (int rt = 0; rt < 2; ++rt)
#pragma unroll
            for (int reg = 0; reg < 4; ++reg) {
                int r = wave * 32 + rt * 16 + quad * 4 + reg;
                if (r < rows) {
                    float v = acc[rt][ct][reg] + bv;
                    if (OUTH1) ((__half*)out1)[(size_t)(r0 + r) * 128 + colI] = __float2half(v);
                    else       ((float*)out1)[(size_t)(r0 + r) * 128 + colI] = v;
                }
            }
    }
}

// ---------------- GEMM: (n,34) @ (34,128) + bias (fp32 VALU) ----------
__global__ __launch_bounds__(256) void k_gemm_emb(const float* __restrict__ A,
                                                  const float* __restrict__ W,
                                                  const float* __restrict__ bias,
                                                  float* __restrict__ out, int nRows) {
    __shared__ float As[64 * NF];
    int r0 = blockIdx.x * 64;
    int rows = nRows - r0; if (rows > 64) rows = 64;
    int total = rows * NF;
    for (int idx = threadIdx.x; idx < 64 * NF; idx += 256)
        As[idx] = (idx < total) ? A[(size_t)r0 * NF + idx] : 0.f;
    __syncthreads();
    int tx = threadIdx.x & 31, ty = threadIdx.x >> 5;
    const float4* W4 = (const float4*)W;
    float acc[8][4];
#pragma unroll
    for (int j = 0; j < 8; ++j)
#pragma unroll
        for (int i = 0; i < 4; ++i) acc[j][i] = 0.f;
#pragma unroll 2
    for (int k = 0; k < NF; ++k) {
        float4 w = W4[k * 32 + tx];
#pragma unroll
        for (int j = 0; j < 8; ++j) {
            float a = As[(ty * 8 + j) * NF + k];
            acc[j][0] += a * w.x; acc[j][1] += a * w.y;
            acc[j][2] += a * w.z; acc[j][3] += a * w.w;
        }
    }
    float4 b = ((const float4*)bias)[tx];
#pragma unroll
    for (int j = 0; j < 8; ++j) {
        int r = ty * 8 + j;
        if (r < rows) {
            float4 o = make_float4(acc[j][0] + b.x, acc[j][1] + b.y,
                                   acc[j][2] + b.z, acc[j][3] + b.w);
            ((float4*)out)[(size_t)(r0 + r) * 32 + tx] = o;
        }
    }
}

// ---------------- BN statistics (per-column sum / sumsq) ----------------
__global__ __launch_bounds__(256) void k_stats(const float* __restrict__ src, int nRows,
                                               float* __restrict__ st) {
    int c = threadIdx.x & 127;
    int sub = threadIdx.x >> 7;  // 0/1
    int r0 = blockIdx.x * 128;
    int rend = r0 + 128; if (rend > nRows) rend = nRows;
    float s = 0.f, ss = 0.f;
    for (int r = r0 + sub; r < rend; r += 2) {
        float v = src[(size_t)r * 128 + c];
        s += v; ss += v * v;
    }
    atomicAdd(&st[c], s);
    atomicAdd(&st[128 + c], ss);
}

// ---- FUSED GAT edge pass: quarter-wave per edge (16 lanes x 8 chans), fp16 score ----
// head = l16>>2 (4 lanes/head, 32 chans); dot reduction = 2 shfl_xor (1,2).
// 4 edges in flight per wave instruction stream; 16B gathers.
__global__ __launch_bounds__(256) void k_gat_aggr(const __half* __restrict__ xl,
                                                  const __half* __restrict__ xr,
                                                  const float* __restrict__ att,
                                                  const float* __restrict__ gbias_l,
                                                  const int* __restrict__ rp,
                                                  const int2* __restrict__ edg,
                                                  float* __restrict__ out) {
    int lane = threadIdx.x & 63;
    int node = blockIdx.x * 4 + (threadIdx.x >> 6);
    if (node >= NN) return;
    int q = lane >> 4;      // edge strand 0..3
    int l16 = lane & 15;
    int c8 = l16 * 8;
    // preload xr[node] (8 chans) and att (8 chans) as packed half2
    float4 xrr = *(const float4*)&xr[(unsigned)node * 128u + c8];
    hv2 xrh[4] = {*(hv2*)&xrr.x, *(hv2*)&xrr.y, *(hv2*)&xrr.z, *(hv2*)&xrr.w};
    float4 atA = *(const float4*)&att[c8];
    float4 atB = *(const float4*)&att[c8 + 4];
    hv2 ath[4] = {{(_Float16)atA.x, (_Float16)atA.y}, {(_Float16)atA.z, (_Float16)atA.w},
                  {(_Float16)atB.x, (_Float16)atB.y}, {(_Float16)atB.z, (_Float16)atB.w}};
    const hv2 hz = {(_Float16)0.f, (_Float16)0.f};
    const hv2 hs = {(_Float16)LSLOPE, (_Float16)LSLOPE};
    int s0 = rp[node];
    int T = rp[node + 1] - s0 + 1;  // logical edge T-1 is the self loop
    float a[8] = {0.f, 0.f, 0.f, 0.f, 0.f, 0.f, 0.f, 0.f};
    float l = 0.f;
    auto body = [&](int j) {
        bool self = (j == T - 1);
        int src = self ? node : edg[s0 + j].x;
        float4 raw = *(const float4*)&xl[(unsigned)src * 128u + c8];
        hv2 f[4] = {*(hv2*)&raw.x, *(hv2*)&raw.y, *(hv2*)&raw.z, *(hv2*)&raw.w};
        float p = 0.f;
#pragma unroll
        for (int k = 0; k < 4; ++k) {
            hv2 e = f[k] + xrh[k];
            hv2 lk = __builtin_elementwise_max(e, hz) + hs * __builtin_elementwise_min(e, hz);
            p = fdot2(lk, ath[k], p);
        }
        p += __shfl_xor(p, 1); p += __shfl_xor(p, 2);
        float w = __expf(p);
#pragma unroll
        for (int k = 0; k < 4; ++k) {
            a[2 * k] += w * (float)f[k].x;
            a[2 * k + 1] += w * (float)f[k].y;
        }
        l += w;
    };
    int j = q;
    for (; j + 4 < T; j += 8) { body(j); body(j + 4); }
    for (; j < T; j += 4) body(j);
#pragma unroll
    for (int k = 0; k < 8; ++k) { a[k] += __shfl_xor(a[k], 16); a[k] += __shfl_xor(a[k], 32); }
    l += __shfl_xor(l, 16); l += __shfl_xor(l, 32);
    if (q == 0) {
        float inv = 1.f / (l + 1e-16f);
        float4 gb0 = *(const float4*)&gbias_l[c8];
        float4 gb1 = *(const float4*)&gbias_l[c8 + 4];
        float4 o0 = make_float4(a[0] * inv + gb0.x, a[1] * inv + gb0.y,
                                a[2] * inv + gb0.z, a[3] * inv + gb0.w);
        float4 o1 = make_float4(a[4] * inv + gb1.x, a[5] * inv + gb1.y,
                                a[6] * inv + gb1.z, a[7] * inv + gb1.w);
        *(float4*)&out[(unsigned)node * 128u + c8] = o0;
        *(float4*)&out[(unsigned)node * 128u + c8 + 4] = o1;
    }
}

// ---- FUSED Transformer edge pass: quarter-wave per edge, fdot2 QK, fp16 skip -------
__global__ __launch_bounds__(256) void k_trans_aggr(const __half* __restrict__ qh,
                                                    const __half* __restrict__ kh,
                                                    const __half* __restrict__ vv,
                                                    const __half* __restrict__ sT,
                                                    const int* __restrict__ rp,
                                                    const int2* __restrict__ edg,
                                                    float* __restrict__ out) {
    int lane = threadIdx.x & 63;
    int node = blockIdx.x * 4 + (threadIdx.x >> 6);
    if (node >= NN) return;
    int q = lane >> 4;
    int l16 = lane & 15;
    int c8 = l16 * 8;
    float4 qr = *(const float4*)&qh[(unsigned)node * 128u + c8];
    const hv2 hinv = {(_Float16)INV_SQRT_C, (_Float16)INV_SQRT_C};
    hv2 qv[4] = {(*(hv2*)&qr.x) * hinv, (*(hv2*)&qr.y) * hinv,
                 (*(hv2*)&qr.z) * hinv, (*(hv2*)&qr.w) * hinv};
    int s0 = rp[node];
    int T = rp[node + 1] - s0;
    float a[8] = {0.f, 0.f, 0.f, 0.f, 0.f, 0.f, 0.f, 0.f};
    float l = 0.f;
    auto body = [&](int j) {
        int src = edg[s0 + j].x;
        float4 kraw = *(const float4*)&kh[(unsigned)src * 128u + c8];
        float4 vraw = *(const float4*)&vv[(unsigned)src * 128u + c8];
        hv2 kv[4] = {*(hv2*)&kraw.x, *(hv2*)&kraw.y, *(hv2*)&kraw.z, *(hv2*)&kraw.w};
        float p = 0.f;
#pragma unroll
        for (int k = 0; k < 4; ++k) p = fdot2(kv[k], qv[k], p);
        p += __shfl_xor(p, 1); p += __shfl_xor(p, 2);
        float w = __expf(p);
        hv2 vvv[4] = {*(hv2*)&vraw.x, *(hv2*)&vraw.y, *(hv2*)&vraw.z, *(hv2*)&vraw.w};
#pragma unroll
        for (int k = 0; k < 4; ++k) {
            a[2 * k] += w * (float)vvv[k].x;
            a[2 * k + 1] += w * (float)vvv[k].y;
        }
        l += w;
    };
    int j = q;
    for (; j + 4 < T; j += 8) { body(j); body(j + 4); }
    for (; j < T; j += 4) body(j);
#pragma unroll
    for (int k = 0; k < 8; ++k) { a[k] += __shfl_xor(a[k], 16); a[k] += __shfl_xor(a[k], 32); }
    l += __shfl_xor(l, 16); l += __shfl_xor(l, 32);
    if (q == 0) {
        float inv = 1.f / (l + 1e-16f);
        float4 straw = *(const float4*)&sT[(unsigned)node * 128u + c8];
        hv2 st[4] = {*(hv2*)&straw.x, *(hv2*)&straw.y, *(hv2*)&straw.z, *(hv2*)&straw.w};
        float4 o0 = make_float4(a[0] * inv + (float)st[0].x, a[1] * inv + (float)st[0].y,
                                a[2] * inv + (float)st[1].x, a[3] * inv + (float)st[1].y);
        float4 o1 = make_float4(a[4] * inv + (float)st[2].x, a[5] * inv + (float)st[2].y,
                                a[6] * inv + (float)st[3].x, a[7] * inv + (float)st[3].y);
        *(float4*)&out[(unsigned)node * 128u + c8] = o0;
        *(float4*)&out[(unsigned)node * 128u + c8 + 4] = o1;
    }
}

// ---- pooling phase 1 WITH FUSED final BN: v = bn(src) + res, per-graph sum/max ----
// Each thread owns one column c, so BN scale/shift is computed once per thread.
__global__ __launch_bounds__(256) void k_pool_part(const float* __restrict__ src,
                                                   const float* __restrict__ res,
                                                   const float* __restrict__ st,
                                                   const float* __restrict__ g,
                                                   const float* __restrict__ b,
                                                   const int* __restrict__ batch,
                                                   float* __restrict__ psum,
                                                   unsigned* __restrict__ pmax) {
    __shared__ int bs[64];
    int r0 = blockIdx.x * 64;
    if (threadIdx.x < 64) {
        int r = r0 + threadIdx.x;
        bs[threadIdx.x] = (r < NN) ? batch[r] : -1;
    }
    __syncthreads();
    int c = threadIdx.x & 127;
    int sub = threadIdx.x >> 7;
    const float invn = 1.f / NN;
    float mean = st[c] * invn;
    float var = fmaxf(st[128 + c] * invn - mean * mean, 0.f);
    float scv = g[c] * rsqrtf(var + EPSB);
    float shv = b[c] - mean * scv;
    int curg = -1;
    float s = 0.f, fmx = -INFINITY;
    for (int i = sub; i < 64; i += 2) {
        int r = r0 + i;
        if (r >= NN) break;
        int gr = bs[i];
        if (gr != curg) {
            if (curg >= 0) {
                atomicAdd(&psum[curg * 128 + c], s);
                atomicMax(&pmax[curg * 128 + c], fenc(fmx));
            }
            curg = gr; s = 0.f; fmx = -INFINITY;
        }
        float v = src[(size_t)r * 128 + c] * scv + shv + res[(size_t)r * 128 + c];
        s += v; fmx = fmaxf(fmx, v);
    }
    if (curg >= 0) {
        atomicAdd(&psum[curg * 128 + c], s);
        atomicMax(&pmax[curg * 128 + c], fenc(fmx));
    }
}

// ---------------- pooling phase 2: finalize ----------------
__global__ __launch_bounds__(128) void k_pool_final(const float* __restrict__ psum,
                                                    const unsigned* __restrict__ pmax,
                                                    const int* __restrict__ batch,
                                                    float* __restrict__ h) {
    __shared__ int se[2];
    int g = blockIdx.x;
    if (threadIdx.x == 0) {
        int lo = 0, hi = NN;
        while (lo < hi) { int mid = (lo + hi) >> 1; if (batch[mid] < g) lo = mid + 1; else hi = mid; }
        se[0] = lo;
        hi = NN;
        while (lo < hi) { int mid = (lo + hi) >> 1; if (batch[mid] < g + 1) lo = mid + 1; else hi = mid; }
        se[1] = lo;
    }
    __syncthreads();
    int cnt = se[1] - se[0];
    int c = threadIdx.x;
    float xm = psum[g * 128 + c] / fmaxf((float)cnt, 1.f);
    float xx = (cnt > 0) ? fdec(pmax[g * 128 + c]) : 0.f;
    h[g * 256 + c] = xm;
    h[g * 256 + 128 + c] = xx;
}

// ---------------- head ----------------
__global__ __launch_bounds__(128) void k_head1(const float* __restrict__ h,
                                               const float* __restrict__ W,
                                               const float* __restrict__ b,
                                               float* __restrict__ t1) {
    __shared__ float hr[256];
    int row = blockIdx.x;
    int t = threadIdx.x;
    hr[t] = h[row * 256 + t];
    hr[t + 128] = h[row * 256 + 128 + t];
    __syncthreads();
    float acc = b[t];
#pragma unroll 4
    for (int k = 0; k < 256; ++k) acc += hr[k] * W[k * 128 + t];
    t1[row * 128 + t] = acc;
}

__global__ __launch_bounds__(64) void k_head2(const float* __restrict__ t1,
                                              const float* __restrict__ st,
                                              const float* __restrict__ og,
                                              const float* __restrict__ obe,
                                              const float* __restrict__ W2,
                                              const float* __restrict__ b2,
                                              const float* __restrict__ W3,
                                              const float* __restrict__ b3,
                                              float* __restrict__ out) {
    __shared__ float v[128];
    int row = blockIdx.x, t = threadIdx.x;
    const float invn = 1.f / NG;
#pragma unroll
    for (int half = 0; half < 2; ++half) {
        int ch = t + half * 64;
        float mean = st[ch] * invn;
        float var = fmaxf(st[128 + ch] * invn - mean * mean, 0.f);
        float scv = og[ch] * rsqrtf(var + EPSB);
        float shv = obe[ch] - mean * scv;
        float a = t1[row * 128 + ch] * scv + shv;
        v[ch] = fmaxf(a, 0.f);
    }
    __syncthreads();
    float acc = b2[t];
#pragma unroll 4
    for (int k = 0; k < 128; ++k) acc += v[k] * W2[k * 64 + t];
    float p = fmaxf(acc, 0.f) * W3[t];
    p += __shfl_xor(p, 1); p += __shfl_xor(p, 2); p += __shfl_xor(p, 4);
    p += __shfl_xor(p, 8); p += __shfl_xor(p, 16); p += __shfl_xor(p, 32);
    if (t == 0) out[row] = p + b3[0];
}

// ---------------- launch ----------------
extern "C" void kernel_launch(void* const* d_in, const int* in_sizes, int n_in,
                              void* d_out, int out_size, void* d_ws, size_t ws_size,
                              hipStream_t stream) {
    const float* x_in   = (const float*)d_in[0];
    const int*   ei     = (const int*)d_in[1];
    const int*   batch  = (const int*)d_in[2];
    const float* emb_W  = (const float*)d_in[3];
    const float* emb_b  = (const float*)d_in[4];
    const float* emb_g  = (const float*)d_in[5];
    const float* emb_be = (const float*)d_in[6];
    const float* gWl    = (const float*)d_in[7];
    const float* gWr    = (const float*)d_in[8];
    const float* gbl    = (const float*)d_in[9];
    const float* gbr    = (const float*)d_in[10];
    const float* gatt   = (const float*)d_in[11];
    const float* gbias  = (const float*)d_in[12];
    const float* gg     = (const float*)d_in[13];
    const float* gbe    = (const float*)d_in[14];
    const float* tWq    = (const float*)d_in[15];
    const float* tWk    = (const float*)d_in[16];
    const float* tWv    = (const float*)d_in[17];
    const float* tWs    = (const float*)d_in[18];
    const float* tbq    = (const float*)d_in[19];
    const float* tbk    = (const float*)d_in[20];
    const float* tbv    = (const float*)d_in[21];
    const float* tbs    = (const float*)d_in[22];
    const float* tg     = (const float*)d_in[23];
    const float* tbe    = (const float*)d_in[24];
    const float* oW1    = (const float*)d_in[25];
    const float* ob1    = (const float*)d_in[26];
    const float* og     = (const float*)d_in[27];
    const float* obe    = (const float*)d_in[28];
    const float* oW2    = (const float*)d_in[29];
    const float* ob2    = (const float*)d_in[30];
    const float* oW3    = (const float*)d_in[31];
    const float* ob3    = (const float*)d_in[32];
    float* out = (float*)d_out;

    const size_t NDsz = (size_t)NN * 128;
    float* x     = (float*)d_ws;       // ping
    float* bA    = x + NDsz;           // pong (also emb out)
    float* bC    = bA + NDsz;          // aggr output / pre-BN
    float* stats = bC + NDsz;          // 7 * 256 floats
    float* hpool = stats + 7 * 256;    // 256*256
    float* t1    = hpool + 65536;      // 256*128
    float* scb   = t1 + 32768;         // hosts rank (NE ints)
    __half* xlh  = (__half*)(scb + (size_t)(NE + NN) * 4);  // xl / K
    __half* xrh  = xlh + NDsz;         // xr / Q
    __half* vh   = xrh + NDsz;         // V
    __half* sh   = vh + NDsz;          // S skip (fp16)
    short* Wt    = (short*)(sh + NDsz);  // 12 * 128*128 bf16 transposed
    int* deg     = (int*)(Wt + 12 * 16384);
    int* rp      = deg + NN;
    int* cursor  = rp + NN + 1;        // kept (dead) to preserve proven layout
    int2* edg    = (int2*)(cursor + NN);  // NE+64 packed (src,dst)
    int* bsum    = (int*)(edg + NE + 64);
    int* boff    = bsum + 256;
    float* psum  = (float*)(boff + 256);            // NG*128
    unsigned* pmax = (unsigned*)(psum + NG * 128);  // NG*128
    int* rank    = (int*)scb;          // aliases scb

    hipMemsetAsync(deg, 0, NN * sizeof(int), stream);
    hipMemsetAsync(stats, 0, 7 * 256 * sizeof(float), stream);
    hipMemsetAsync(psum, 0, NG * 128 * 2 * sizeof(float), stream);  // psum + pmax

    // weight prep (bf16 transposed)
    k_prep<<<12, 256, 0, stream>>>(gWl, gWr, tWq, tWk, tWv, tWs, Wt);

    // CSR by destination (rank-based; k_fill is atomic-free)
    const int S4 = (NE + 3) / 4;
    const int gQuarter = (S4 + 255) / 256;
    k_deg<<<gQuarter, 256, 0, stream>>>(ei, deg, rank);
    k_scan1<<<NB, 256, 0, stream>>>(deg, bsum);
    k_scan2<<<1, 256, 0, stream>>>(bsum, boff, rp);
    k_scan3<<<NB, 256, 0, stream>>>(deg, boff, rp);
    k_fill<<<gQuarter, 256, 0, stream>>>(ei, rp, rank, edg);

    const int gEmb  = (NN + 63) / 64;
    const int gGemm = (NN + 127) / 128;
    const int gStat = (NN + 127) / 128;
    const int gNode = (NN + 3) / 4;
    const int gPool = (NN + 63) / 64;

    // embedding GEMM -> bA; stats0
    k_gemm_emb<<<gEmb, 256, 0, stream>>>(x_in, emb_W, emb_b, bA, NN);
    k_stats<<<gStat, 256, 0, stream>>>(bA, NN, stats);

    // ping-pong feature buffers: residual source alternates x <-> bA
    k_gemm2bn<1, 1, 0, 1><<<gGemm, 256, 0, stream>>>(bA, nullptr, x, stats, emb_g, emb_be,
                                                     Wt + (size_t)0 * 16384, Wt + (size_t)4 * 16384,
                                                     gbl + 0 * 128, gbr + 0 * 128, xlh, xrh, NN);
    k_gat_aggr<<<gNode, 256, 0, stream>>>(xlh, xrh, gatt + 0 * 128, gbias + 0 * 128, rp, edg, bC);
    k_stats<<<gStat, 256, 0, stream>>>(bC, NN, stats + 1 * 256);
    k_gemm2bn<1, 1, 1, 1><<<gGemm, 256, 0, stream>>>(bC, x, bA, stats + 1 * 256, gg + 0 * 128, gbe + 0 * 128,
                                                     Wt + (size_t)1 * 16384, Wt + (size_t)5 * 16384,
                                                     gbl + 1 * 128, gbr + 1 * 128, xlh, xrh, NN);
    k_gat_aggr<<<gNode, 256, 0, stream>>>(xlh, xrh, gatt + 1 * 128, gbias + 1 * 128, rp, edg, bC);
    k_stats<<<gStat, 256, 0, stream>>>(bC, NN, stats + 2 * 256);
    k_gemm2bn<1, 1, 1, 1><<<gGemm, 256, 0, stream>>>(bC, bA, x, stats + 2 * 256, gg + 1 * 128, gbe + 1 * 128,
                                                     Wt + (size_t)2 * 16384, Wt + (size_t)6 * 16384,
                                                     gbl + 2 * 128, gbr + 2 * 128, xlh, xrh, NN);
    k_gat_aggr<<<gNode, 256, 0, stream>>>(xlh, xrh, gatt + 2 * 128, gbias + 2 * 128, rp, edg, bC);
    k_stats<<<gStat, 256, 0, stream>>>(bC, NN, stats + 3 * 256);
    k_gemm2bn<1, 1, 1, 1><<<gGemm, 256, 0, stream>>>(bC, x, bA, stats + 3 * 256, gg + 2 * 128, gbe + 2 * 128,
                                                     Wt + (size_t)3 * 16384, Wt + (size_t)7 * 16384,
                                                     gbl + 3 * 128, gbr + 3 * 128, xlh, xrh, NN);
    k_gat_aggr<<<gNode, 256, 0, stream>>>(xlh, xrh, gatt + 3 * 128, gbias + 3 * 128, rp, edg, bC);
    k_stats<<<gStat, 256, 0, stream>>>(bC, NN, stats + 4 * 256);

    // TransformerConv: Q/K writes x; V/S skips the duplicate xout write (XOUT=0)
    k_gemm2bn<1, 1, 1, 1><<<gGemm, 256, 0, stream>>>(bC, bA, x, stats + 4 * 256, gg + 3 * 128, gbe + 3 * 128,
                                                     Wt + (size_t)8 * 16384, Wt + (size_t)9 * 16384,
                                                     tbq, tbk, xrh, xlh, NN);   // Q, K
    k_gemm2bn<1, 1, 1, 0><<<gGemm, 256, 0, stream>>>(bC, bA, nullptr, stats + 4 * 256, gg + 3 * 128, gbe + 3 * 128,
                                                     Wt + (size_t)10 * 16384, Wt + (size_t)11 * 16384,
                                                     tbv, tbs, vh, sh, NN);     // V, S(skip, fp16)
    k_trans_aggr<<<gNode, 256, 0, stream>>>(xrh, xlh, vh, sh, rp, edg, bC);
    k_stats<<<gStat, 256, 0, stream>>>(bC, NN, stats + 5 * 256);

    // pooling (with fused final BN: v = bn(bC) + x) + head
    k_pool_part<<<gPool, 256, 0, stream>>>(bC, x, stats + 5 * 256, tg, tbe, batch, psum, pmax);
    k_pool_final<<<NG, 128, 0, stream>>>(psum, pmax, batch, hpool);
    k_head1<<<NG, 128, 0, stream>>>(hpool, oW1, ob1, t1);
    k_stats<<<(NG + 127) / 128, 256, 0, stream>>>(t1, NG, stats + 6 * 256);
    k_head2<<<NG, 64, 0, stream>>>(t1, stats + 6 * 256, og, obe, oW2, ob2, oW3, ob3, out);
}

// Round 20
// 905.301 us; speedup vs baseline: 1.0743x; 1.0149x over previous
//
#include <hip/hip_runtime.h>
#include <hip/hip_fp16.h>

// ---------------- constants ----------------
namespace {
constexpr int NN = 50000;   // nodes
constexpr int NE = 800000;  // edges
constexpr int NG = 256;     // graphs
constexpr int NF = 34;      // in features
constexpr int NL = 4;       // GAT layers
constexpr int NB = (NN + 255) / 256;  // scan blocks = 196
}
#define EPSB 1e-5f
#define LSLOPE 0.2f
#define INV_SQRT_C 0.17677669529663687f  // 1/sqrt(32)

typedef short bf16x8 __attribute__((ext_vector_type(8)));
typedef float f32x4 __attribute__((ext_vector_type(4)));
typedef _Float16 hv2 __attribute__((ext_vector_type(2)));

static __device__ __forceinline__ short f2bf(float f) {
    unsigned int u = __float_as_uint(f);
    u = (u + 0x7fff + ((u >> 16) & 1)) >> 16;  // RNE
    return (short)u;
}
// order-preserving float<->uint for atomicMax; all encodings > 0, so memset-0 = -inf
static __device__ __forceinline__ unsigned fenc(float x) {
    unsigned u = __float_as_uint(x);
    return (u & 0x80000000u) ? ~u : (u | 0x80000000u);
}
static __device__ __forceinline__ float fdec(unsigned u) {
    return __uint_as_float((u & 0x80000000u) ? (u ^ 0x80000000u) : ~u);
}
// v_dot2_f32_f16: c += a.x*b.x + a.y*b.y (fp32 accumulate)
static __device__ __forceinline__ float fdot2(hv2 a, hv2 b, float c) {
    return __builtin_amdgcn_fdot2(a, b, c, false);
}

// ---------------- CSR build: 4 DISJOINT strands/thread (tid<S guard is load-bearing)
__global__ __launch_bounds__(256) void k_deg(const int* __restrict__ ei,
                                             int* __restrict__ deg,
                                             int* __restrict__ rank) {
    int tid = blockIdx.x * 256 + threadIdx.x;
    const int S = (NE + 3) / 4;  // 200000
    if (tid >= S) return;
#pragma unroll
    for (int k = 0; k < 4; ++k) {
        int e = tid + k * S;
        if (e < NE) rank[e] = atomicAdd(&deg[ei[NE + e]], 1);
    }
}

__global__ __launch_bounds__(256) void k_scan1(const int* __restrict__ deg, int* __restrict__ bsum) {
    __shared__ int sm[256];
    int i = blockIdx.x * 256 + threadIdx.x;
    sm[threadIdx.x] = (i < NN) ? deg[i] : 0;
    __syncthreads();
    for (int off = 128; off > 0; off >>= 1) {
        if (threadIdx.x < off) sm[threadIdx.x] += sm[threadIdx.x + off];
        __syncthreads();
    }
    if (threadIdx.x == 0) bsum[blockIdx.x] = sm[0];
}

__global__ __launch_bounds__(256) void k_scan2(const int* __restrict__ bsum,
                                               int* __restrict__ boff, int* __restrict__ rp) {
    __shared__ int sm[256];
    int t = threadIdx.x;
    int v = (t < NB) ? bsum[t] : 0;
    sm[t] = v;
    __syncthreads();
    for (int off = 1; off < 256; off <<= 1) {
        int u = (t >= off) ? sm[t - off] : 0;
        __syncthreads();
        sm[t] += u;
        __syncthreads();
    }
    if (t < NB) boff[t] = sm[t] - v;
    if (t == 255) rp[NN] = sm[255];
}

__global__ __launch_bounds__(256) void k_scan3(const int* __restrict__ deg,
                                               const int* __restrict__ boff,
                                               int* __restrict__ rp) {
    __shared__ int sm[256];
    int i = blockIdx.x * 256 + threadIdx.x;
    int t = threadIdx.x;
    int v = (i < NN) ? deg[i] : 0;
    sm[t] = v;
    __syncthreads();
    for (int off = 1; off < 256; off <<= 1) {
        int u = (t >= off) ? sm[t - off] : 0;
        __syncthreads();
        sm[t] += u;
        __syncthreads();
    }
    if (i < NN) rp[i] = boff[blockIdx.x] + sm[t] - v;
}

// atomic-free scatter: p = rp[d] + rank[e]; 4 disjoint strands per thread
__global__ __launch_bounds__(256) void k_fill(const int* __restrict__ ei,
                                              const int* __restrict__ rp,
                                              const int* __restrict__ rank,
                                              int2* __restrict__ edg) {
    int tid = blockIdx.x * 256 + threadIdx.x;
    const int S = (NE + 3) / 4;
    if (tid >= S) return;
#pragma unroll
    for (int k = 0; k < 4; ++k) {
        int e = tid + k * S;
        if (e < NE) {
            int s = ei[e];
            int d = ei[NE + e];
            int p = rp[d] + rank[e];
            edg[p] = make_int2(s, d);
        }
    }
}

// ---------------- weight prep: 12x (128,128) fp32 -> transposed bf16 ----------------
__global__ __launch_bounds__(256) void k_prep(const float* __restrict__ gWl,
                                              const float* __restrict__ gWr,
                                              const float* __restrict__ tWq,
                                              const float* __restrict__ tWk,
                                              const float* __restrict__ tWv,
                                              const float* __restrict__ tWs,
                                              short* __restrict__ dst) {
    int m = blockIdx.x;
    const float* src;
    if (m < 4) src = gWl + m * 16384;
    else if (m < 8) src = gWr + (m - 4) * 16384;
    else if (m == 8) src = tWq;
    else if (m == 9) src = tWk;
    else if (m == 10) src = tWv;
    else src = tWs;
    short* d = dst + m * 16384;
    for (int i = threadIdx.x; i < 16384; i += 256) {
        int n = i >> 7, k = i & 127;
        d[i] = f2bf(src[k * 128 + n]);  // Wt[n][k] = W[k][n]
    }
}

// ------- pair-fused MFMA GEMM with FUSED BN(+ReLU)+residual in the A-stage ----------
template <int OUTH0, int OUTH1, int RES, int XOUT>
__global__ __launch_bounds__(256) void k_gemm2bn(const float* __restrict__ src,
                                                 const float* __restrict__ res,
                                                 float* __restrict__ xout,
                                                 const float* __restrict__ st,
                                                 const float* __restrict__ g,
                                                 const float* __restrict__ b,
                                                 const short* __restrict__ Wt0,
                                                 const short* __restrict__ Wt1,
                                                 const float* __restrict__ bias0,
                                                 const float* __restrict__ bias1,
                                                 void* __restrict__ out0,
                                                 void* __restrict__ out1, int nRows) {
    __shared__ short As[128 * 136];
    __shared__ short Bs[128 * 136];
    __shared__ float scsh[256];
    const float invn = 1.f / NN;
    if (threadIdx.x < 128) {
        int c = threadIdx.x;
        float mean = st[c] * invn;
        float var = fmaxf(st[128 + c] * invn - mean * mean, 0.f);
        float s = g[c] * rsqrtf(var + EPSB);
        scsh[c] = s;
        scsh[128 + c] = b[c] - mean * s;
    }
    {
        const int4* Wt4 = (const int4*)Wt0;
        for (int idx = threadIdx.x; idx < 2048; idx += 256) {
            int row = idx >> 4, c8 = idx & 15;
            *(int4*)&Bs[row * 136 + c8 * 8] = Wt4[idx];
        }
    }
    __syncthreads();  // scsh ready
    int r0 = blockIdx.x * 128;
    int rows = nRows - r0; if (rows > 128) rows = 128;
    for (int idx = threadIdx.x; idx < 2048; idx += 256) {
        int r = idx >> 4, c8 = idx & 15;
        short4 sa = {0, 0, 0, 0}, sb = {0, 0, 0, 0};
        if (r < rows) {
            size_t base = (size_t)(r0 + r) * 128 + c8 * 8;
            float4 v0 = *(const float4*)&src[base];
            float4 v1 = *(const float4*)&src[base + 4];
            int c = c8 * 8;
            v0.x = fmaxf(v0.x * scsh[c + 0] + scsh[128 + c + 0], 0.f);
            v0.y = fmaxf(v0.y * scsh[c + 1] + scsh[128 + c + 1], 0.f);
            v0.z = fmaxf(v0.z * scsh[c + 2] + scsh[128 + c + 2], 0.f);
            v0.w = fmaxf(v0.w * scsh[c + 3] + scsh[128 + c + 3], 0.f);
            v1.x = fmaxf(v1.x * scsh[c + 4] + scsh[128 + c + 4], 0.f);
            v1.y = fmaxf(v1.y * scsh[c + 5] + scsh[128 + c + 5], 0.f);
            v1.z = fmaxf(v1.z * scsh[c + 6] + scsh[128 + c + 6], 0.f);
            v1.w = fmaxf(v1.w * scsh[c + 7] + scsh[128 + c + 7], 0.f);
            if (RES) {
                float4 rr0 = *(const float4*)&res[base];
                float4 rr1 = *(const float4*)&res[base + 4];
                v0.x += rr0.x; v0.y += rr0.y; v0.z += rr0.z; v0.w += rr0.w;
                v1.x += rr1.x; v1.y += rr1.y; v1.z += rr1.z; v1.w += rr1.w;
            }
            if (XOUT) {
                *(float4*)&xout[base] = v0;
                *(float4*)&xout[base + 4] = v1;
            }
            sa.x = f2bf(v0.x); sa.y = f2bf(v0.y); sa.z = f2bf(v0.z); sa.w = f2bf(v0.w);
            sb.x = f2bf(v1.x); sb.y = f2bf(v1.y); sb.z = f2bf(v1.z); sb.w = f2bf(v1.w);
        }
        *(short4*)&As[r * 136 + c8 * 8] = sa;
        *(short4*)&As[r * 136 + c8 * 8 + 4] = sb;
    }
    __syncthreads();
    int lane = threadIdx.x & 63, wave = threadIdx.x >> 6;
    int n16 = lane & 15, quad = lane >> 4;
    bf16x8 af[2][4];
#pragma unroll
    for (int rt = 0; rt < 2; ++rt)
#pragma unroll
        for (int kc = 0; kc < 4; ++kc)
            af[rt][kc] = *(const bf16x8*)&As[(wave * 32 + rt * 16 + n16) * 136 + kc * 32 + quad * 8];

    f32x4 acc[2][8];
#pragma unroll
    for (int rt = 0; rt < 2; ++rt)
#pragma unroll
        for (int ct = 0; ct < 8; ++ct) acc[rt][ct] = (f32x4){0.f, 0.f, 0.f, 0.f};
#pragma unroll
    for (int ct = 0; ct < 8; ++ct)
#pragma unroll
        for (int kc = 0; kc < 4; ++kc) {
            bf16x8 bf = *(const bf16x8*)&Bs[(ct * 16 + n16) * 136 + kc * 32 + quad * 8];
            acc[0][ct] = __builtin_amdgcn_mfma_f32_16x16x32_bf16(af[0][kc], bf, acc[0][ct], 0, 0, 0);
            acc[1][ct] = __builtin_amdgcn_mfma_f32_16x16x32_bf16(af[1][kc], bf, acc[1][ct], 0, 0, 0);
        }
#pragma unroll
    for (int ct = 0; ct < 8; ++ct) {
        int colI = ct * 16 + n16;
        float bv = bias0[colI];
#pragma unroll
        for (int rt = 0; rt < 2; ++rt)
#pragma unroll
            for (int reg = 0; reg < 4; ++reg) {
                int r = wave * 32 + rt * 16 + quad * 4 + reg;  // C/D: col=lane&15, row=quad*4+reg
                if (r < rows) {
                    float v = acc[rt][ct][reg] + bv;
                    if (OUTH0) ((__half*)out0)[(size_t)(r0 + r) * 128 + colI] = __float2half(v);
                    else       ((float*)out0)[(size_t)(r0 + r) * 128 + colI] = v;
                }
            }
    }
    __syncthreads();
    {
        const int4* Wt4 = (const int4*)Wt1;
        for (int idx = threadIdx.x; idx < 2048; idx += 256) {
            int row = idx >> 4, c8 = idx & 15;
            *(int4*)&Bs[row * 136 + c8 * 8] = Wt4[idx];
        }
    }
    __syncthreads();
#pragma unroll
    for (int rt = 0; rt < 2; ++rt)
#pragma unroll
        for (int ct = 0; ct < 8; ++ct) acc[rt][ct] = (f32x4){0.f, 0.f, 0.f, 0.f};
#pragma unroll
    for (int ct = 0; ct < 8; ++ct)
#pragma unroll
        for (int kc = 0; kc < 4; ++kc) {
            bf16x8 bf = *(const bf16x8*)&Bs[(ct * 16 + n16) * 136 + kc * 32 + quad * 8];
            acc[0][ct] = __builtin_amdgcn_mfma_f32_16x16x32_bf16(af[0][kc], bf, acc[0][ct], 0, 0, 0);
            acc[1][ct] = __builtin_amdgcn_mfma_f32_16x16x32_bf16(af[1][kc], bf, acc[1][ct], 0, 0, 0);
        }
#pragma unroll
    for (int ct = 0; ct < 8; ++ct) {
        int colI = ct * 16 + n16;
        float bv = bias1[colI];
#pragma unroll
        for (int rt = 0; rt < 2; ++rt)
#pragma unroll
            for (int reg = 0; reg < 4; ++reg) {
                int r = wave * 32 + rt * 16 + quad * 4 + reg;
                if (r < rows) {
                    float v = acc[rt][ct][reg] + bv;
                    if (OUTH1) ((__half*)out1)[(size_t)(r0 + r) * 128 + colI] = __float2half(v);
                    else       ((float*)out1)[(size_t)(r0 + r) * 128 + colI] = v;
                }
            }
    }
}

// ------- QUAD-fused MFMA GEMM (Q/K/V/S) with BN+residual A-stage; A staged once -----
// Wt points at 4 consecutive 128x128 bf16 matrices; all outputs fp16.
__global__ __launch_bounds__(256) void k_gemm4bn(const float* __restrict__ src,
                                                 const float* __restrict__ res,
                                                 float* __restrict__ xout,
                                                 const float* __restrict__ st,
                                                 const float* __restrict__ g,
                                                 const float* __restrict__ b,
                                                 const short* __restrict__ Wt,
                                                 const float* __restrict__ bq,
                                                 const float* __restrict__ bk,
                                                 const float* __restrict__ bv,
                                                 const float* __restrict__ bs,
                                                 __half* __restrict__ oq,
                                                 __half* __restrict__ ok,
                                                 __half* __restrict__ ov,
                                                 __half* __restrict__ os, int nRows) {
    __shared__ short As[128 * 136];
    __shared__ short Bs[128 * 136];
    __shared__ float scsh[256];
    const float invn = 1.f / NN;
    if (threadIdx.x < 128) {
        int c = threadIdx.x;
        float mean = st[c] * invn;
        float var = fmaxf(st[128 + c] * invn - mean * mean, 0.f);
        float s = g[c] * rsqrtf(var + EPSB);
        scsh[c] = s;
        scsh[128 + c] = b[c] - mean * s;
    }
    __syncthreads();  // scsh ready
    int r0 = blockIdx.x * 128;
    int rows = nRows - r0; if (rows > 128) rows = 128;
    for (int idx = threadIdx.x; idx < 2048; idx += 256) {
        int r = idx >> 4, c8 = idx & 15;
        short4 sa = {0, 0, 0, 0}, sb = {0, 0, 0, 0};
        if (r < rows) {
            size_t base = (size_t)(r0 + r) * 128 + c8 * 8;
            float4 v0 = *(const float4*)&src[base];
            float4 v1 = *(const float4*)&src[base + 4];
            int c = c8 * 8;
            v0.x = fmaxf(v0.x * scsh[c + 0] + scsh[128 + c + 0], 0.f);
            v0.y = fmaxf(v0.y * scsh[c + 1] + scsh[128 + c + 1], 0.f);
            v0.z = fmaxf(v0.z * scsh[c + 2] + scsh[128 + c + 2], 0.f);
            v0.w = fmaxf(v0.w * scsh[c + 3] + scsh[128 + c + 3], 0.f);
            v1.x = fmaxf(v1.x * scsh[c + 4] + scsh[128 + c + 4], 0.f);
            v1.y = fmaxf(v1.y * scsh[c + 5] + scsh[128 + c + 5], 0.f);
            v1.z = fmaxf(v1.z * scsh[c + 6] + scsh[128 + c + 6], 0.f);
            v1.w = fmaxf(v1.w * scsh[c + 7] + scsh[128 + c + 7], 0.f);
            float4 rr0 = *(const float4*)&res[base];
            float4 rr1 = *(const float4*)&res[base + 4];
            v0.x += rr0.x; v0.y += rr0.y; v0.z += rr0.z; v0.w += rr0.w;
            v1.x += rr1.x; v1.y += rr1.y; v1.z += rr1.z; v1.w += rr1.w;
            *(float4*)&xout[base] = v0;
            *(float4*)&xout[base + 4] = v1;
            sa.x = f2bf(v0.x); sa.y = f2bf(v0.y); sa.z = f2bf(v0.z); sa.w = f2bf(v0.w);
            sb.x = f2bf(v1.x); sb.y = f2bf(v1.y); sb.z = f2bf(v1.z); sb.w = f2bf(v1.w);
        }
        *(short4*)&As[r * 136 + c8 * 8] = sa;
        *(short4*)&As[r * 136 + c8 * 8 + 4] = sb;
    }
    int lane = threadIdx.x & 63, wave = threadIdx.x >> 6;
    int n16 = lane & 15, quad = lane >> 4;
    __half* outs[4] = {oq, ok, ov, os};
    const float* biases[4] = {bq, bk, bv, bs};
    bf16x8 af[2][4];
    bool afLoaded = false;
    for (int m = 0; m < 4; ++m) {
        // stage B_m (A is stable after first sync)
        {
            const int4* Wt4 = (const int4*)(Wt + (size_t)m * 16384);
            for (int idx = threadIdx.x; idx < 2048; idx += 256) {
                int row = idx >> 4, c8 = idx & 15;
                *(int4*)&Bs[row * 136 + c8 * 8] = Wt4[idx];
            }
        }
        __syncthreads();
        if (!afLoaded) {
            afLoaded = true;
#pragma unroll
            for (int rt = 0; rt < 2; ++rt)
#pragma unroll
                for (int kc = 0; kc < 4; ++kc)
                    af[rt][kc] = *(const bf16x8*)&As[(wave * 32 + rt * 16 + n16) * 136 + kc * 32 + quad * 8];
        }
        f32x4 acc[2][8];
#pragma unroll
        for (int rt = 0; rt < 2; ++rt)
#pragma unroll
            for (int ct = 0; ct < 8; ++ct) acc[rt][ct] = (f32x4){0.f, 0.f, 0.f, 0.f};
#pragma unroll
        for (int ct = 0; ct < 8; ++ct)
#pragma unroll
            for (int kc = 0; kc < 4; ++kc) {
                bf16x8 bf = *(const bf16x8*)&Bs[(ct * 16 + n16) * 136 + kc * 32 + quad * 8];
                acc[0][ct] = __builtin_amdgcn_mfma_f32_16x16x32_bf16(af[0][kc], bf, acc[0][ct], 0, 0, 0);
                acc[1][ct] = __builtin_amdgcn_mfma_f32_16x16x32_bf16(af[1][kc], bf, acc[1][ct], 0, 0, 0);
            }
        __half* om = outs[m];
        const float* bm = biases[m];
#pragma unroll
        for (int ct = 0; ct < 8; ++ct) {
            int colI = ct * 16 + n16;
            float bv2 = bm[colI];
#pragma unroll
            for (int rt = 0; rt < 2; ++rt)
#pragma unroll
                for (int reg = 0; reg < 4; ++reg) {
                    int r = wave * 32 + rt * 16 + quad * 4 + reg;
                    if (r < rows)
                        om[(size_t)(r0 + r) * 128 + colI] = __float2half(acc[rt][ct][reg] + bv2);
                }
        }
        if (m < 3) __syncthreads();  // protect Bs before next stage
    }
}

// ---------------- GEMM: (n,34) @ (34,128) + bias (fp32 VALU) ----------
__global__ __launch_bounds__(256) void k_gemm_emb(const float* __restrict__ A,
                                                  const float* __restrict__ W,
                                                  const float* __restrict__ bias,
                                                  float* __restrict__ out, int nRows) {
    __shared__ float As[64 * NF];
    int r0 = blockIdx.x * 64;
    int rows = nRows - r0; if (rows > 64) rows = 64;
    int total = rows * NF;
    for (int idx = threadIdx.x; idx < 64 * NF; idx += 256)
        As[idx] = (idx < total) ? A[(size_t)r0 * NF + idx] : 0.f;
    __syncthreads();
    int tx = threadIdx.x & 31, ty = threadIdx.x >> 5;
    const float4* W4 = (const float4*)W;
    float acc[8][4];
#pragma unroll
    for (int j = 0; j < 8; ++j)
#pragma unroll
        for (int i = 0; i < 4; ++i) acc[j][i] = 0.f;
#pragma unroll 2
    for (int k = 0; k < NF; ++k) {
        float4 w = W4[k * 32 + tx];
#pragma unroll
        for (int j = 0; j < 8; ++j) {
            float a = As[(ty * 8 + j) * NF + k];
            acc[j][0] += a * w.x; acc[j][1] += a * w.y;
            acc[j][2] += a * w.z; acc[j][3] += a * w.w;
        }
    }
    float4 b = ((const float4*)bias)[tx];
#pragma unroll
    for (int j = 0; j < 8; ++j) {
        int r = ty * 8 + j;
        if (r < rows) {
            float4 o = make_float4(acc[j][0] + b.x, acc[j][1] + b.y,
                                   acc[j][2] + b.z, acc[j][3] + b.w);
            ((float4*)out)[(size_t)(r0 + r) * 32 + tx] = o;
        }
    }
}

// ---------------- BN statistics (per-column sum / sumsq) ----------------
__global__ __launch_bounds__(256) void k_stats(const float* __restrict__ src, int nRows,
                                               float* __restrict__ st) {
    int c = threadIdx.x & 127;
    int sub = threadIdx.x >> 7;  // 0/1
    int r0 = blockIdx.x * 128;
    int rend = r0 + 128; if (rend > nRows) rend = nRows;
    float s = 0.f, ss = 0.f;
    for (int r = r0 + sub; r < rend; r += 2) {
        float v = src[(size_t)r * 128 + c];
        s += v; ss += v * v;
    }
    atomicAdd(&st[c], s);
    atomicAdd(&st[128 + c], ss);
}

// ---- FUSED GAT edge pass: quarter-wave per edge (16 lanes x 8 chans), fp16 score ----
__global__ __launch_bounds__(256) void k_gat_aggr(const __half* __restrict__ xl,
                                                  const __half* __restrict__ xr,
                                                  const float* __restrict__ att,
                                                  const float* __restrict__ gbias_l,
                                                  const int* __restrict__ rp,
                                                  const int2* __restrict__ edg,
                                                  float* __restrict__ out) {
    int lane = threadIdx.x & 63;
    int node = blockIdx.x * 4 + (threadIdx.x >> 6);
    if (node >= NN) return;
    int q = lane >> 4;      // edge strand 0..3
    int l16 = lane & 15;
    int c8 = l16 * 8;
    float4 xrr = *(const float4*)&xr[(unsigned)node * 128u + c8];
    hv2 xrh[4] = {*(hv2*)&xrr.x, *(hv2*)&xrr.y, *(hv2*)&xrr.z, *(hv2*)&xrr.w};
    float4 atA = *(const float4*)&att[c8];
    float4 atB = *(const float4*)&att[c8 + 4];
    hv2 ath[4] = {{(_Float16)atA.x, (_Float16)atA.y}, {(_Float16)atA.z, (_Float16)atA.w},
                  {(_Float16)atB.x, (_Float16)atB.y}, {(_Float16)atB.z, (_Float16)atB.w}};
    const hv2 hz = {(_Float16)0.f, (_Float16)0.f};
    const hv2 hs = {(_Float16)LSLOPE, (_Float16)LSLOPE};
    int s0 = rp[node];
    int T = rp[node + 1] - s0 + 1;  // logical edge T-1 is the self loop
    float a[8] = {0.f, 0.f, 0.f, 0.f, 0.f, 0.f, 0.f, 0.f};
    float l = 0.f;
    auto body = [&](int j) {
        bool self = (j == T - 1);
        int src = self ? node : edg[s0 + j].x;
        float4 raw = *(const float4*)&xl[(unsigned)src * 128u + c8];
        hv2 f[4] = {*(hv2*)&raw.x, *(hv2*)&raw.y, *(hv2*)&raw.z, *(hv2*)&raw.w};
        float p = 0.f;
#pragma unroll
        for (int k = 0; k < 4; ++k) {
            hv2 e = f[k] + xrh[k];
            hv2 lk = __builtin_elementwise_max(e, hz) + hs * __builtin_elementwise_min(e, hz);
            p = fdot2(lk, ath[k], p);
        }
        p += __shfl_xor(p, 1); p += __shfl_xor(p, 2);
        float w = __expf(p);
#pragma unroll
        for (int k = 0; k < 4; ++k) {
            a[2 * k] += w * (float)f[k].x;
            a[2 * k + 1] += w * (float)f[k].y;
        }
        l += w;
    };
    int j = q;
    for (; j + 4 < T; j += 8) { body(j); body(j + 4); }
    for (; j < T; j += 4) body(j);
#pragma unroll
    for (int k = 0; k < 8; ++k) { a[k] += __shfl_xor(a[k], 16); a[k] += __shfl_xor(a[k], 32); }
    l += __shfl_xor(l, 16); l += __shfl_xor(l, 32);
    if (q == 0) {
        float inv = 1.f / (l + 1e-16f);
        float4 gb0 = *(const float4*)&gbias_l[c8];
        float4 gb1 = *(const float4*)&gbias_l[c8 + 4];
        float4 o0 = make_float4(a[0] * inv + gb0.x, a[1] * inv + gb0.y,
                                a[2] * inv + gb0.z, a[3] * inv + gb0.w);
        float4 o1 = make_float4(a[4] * inv + gb1.x, a[5] * inv + gb1.y,
                                a[6] * inv + gb1.z, a[7] * inv + gb1.w);
        *(float4*)&out[(unsigned)node * 128u + c8] = o0;
        *(float4*)&out[(unsigned)node * 128u + c8 + 4] = o1;
    }
}

// ---- FUSED Transformer edge pass: quarter-wave per edge, fdot2 QK, fp16 skip -------
__global__ __launch_bounds__(256) void k_trans_aggr(const __half* __restrict__ qh,
                                                    const __half* __restrict__ kh,
                                                    const __half* __restrict__ vv,
                                                    const __half* __restrict__ sT,
                                                    const int* __restrict__ rp,
                                                    const int2* __restrict__ edg,
                                                    float* __restrict__ out) {
    int lane = threadIdx.x & 63;
    int node = blockIdx.x * 4 + (threadIdx.x >> 6);
    if (node >= NN) return;
    int q = lane >> 4;
    int l16 = lane & 15;
    int c8 = l16 * 8;
    float4 qr = *(const float4*)&qh[(unsigned)node * 128u + c8];
    const hv2 hinv = {(_Float16)INV_SQRT_C, (_Float16)INV_SQRT_C};
    hv2 qv[4] = {(*(hv2*)&qr.x) * hinv, (*(hv2*)&qr.y) * hinv,
                 (*(hv2*)&qr.z) * hinv, (*(hv2*)&qr.w) * hinv};
    int s0 = rp[node];
    int T = rp[node + 1] - s0;
    float a[8] = {0.f, 0.f, 0.f, 0.f, 0.f, 0.f, 0.f, 0.f};
    float l = 0.f;
    auto body = [&](int j) {
        int src = edg[s0 + j].x;
        float4 kraw = *(const float4*)&kh[(unsigned)src * 128u + c8];
        float4 vraw = *(const float4*)&vv[(unsigned)src * 128u + c8];
        hv2 kv[4] = {*(hv2*)&kraw.x, *(hv2*)&kraw.y, *(hv2*)&kraw.z, *(hv2*)&kraw.w};
        float p = 0.f;
#pragma unroll
        for (int k = 0; k < 4; ++k) p = fdot2(kv[k], qv[k], p);
        p += __shfl_xor(p, 1); p += __shfl_xor(p, 2);
        float w = __expf(p);
        hv2 vvv[4] = {*(hv2*)&vraw.x, *(hv2*)&vraw.y, *(hv2*)&vraw.z, *(hv2*)&vraw.w};
#pragma unroll
        for (int k = 0; k < 4; ++k) {
            a[2 * k] += w * (float)vvv[k].x;
            a[2 * k + 1] += w * (float)vvv[k].y;
        }
        l += w;
    };
    int j = q;
    for (; j + 4 < T; j += 8) { body(j); body(j + 4); }
    for (; j < T; j += 4) body(j);
#pragma unroll
    for (int k = 0; k < 8; ++k) { a[k] += __shfl_xor(a[k], 16); a[k] += __shfl_xor(a[k], 32); }
    l += __shfl_xor(l, 16); l += __shfl_xor(l, 32);
    if (q == 0) {
        float inv = 1.f / (l + 1e-16f);
        float4 straw = *(const float4*)&sT[(unsigned)node * 128u + c8];
        hv2 st[4] = {*(hv2*)&straw.x, *(hv2*)&straw.y, *(hv2*)&straw.z, *(hv2*)&straw.w};
        float4 o0 = make_float4(a[0] * inv + (float)st[0].x, a[1] * inv + (float)st[0].y,
                                a[2] * inv + (float)st[1].x, a[3] * inv + (float)st[1].y);
        float4 o1 = make_float4(a[4] * inv + (float)st[2].x, a[5] * inv + (float)st[2].y,
                                a[6] * inv + (float)st[3].x, a[7] * inv + (float)st[3].y);
        *(float4*)&out[(unsigned)node * 128u + c8] = o0;
        *(float4*)&out[(unsigned)node * 128u + c8 + 4] = o1;
    }
}

// ---- pooling phase 1 WITH FUSED final BN: v = bn(src) + res, per-graph sum/max ----
__global__ __launch_bounds__(256) void k_pool_part(const float* __restrict__ src,
                                                   const float* __restrict__ res,
                                                   const float* __restrict__ st,
                                                   const float* __restrict__ g,
                                                   const float* __restrict__ b,
                                                   const int* __restrict__ batch,
                                                   float* __restrict__ psum,
                                                   unsigned* __restrict__ pmax) {
    __shared__ int bs[64];
    int r0 = blockIdx.x * 64;
    if (threadIdx.x < 64) {
        int r = r0 + threadIdx.x;
        bs[threadIdx.x] = (r < NN) ? batch[r] : -1;
    }
    __syncthreads();
    int c = threadIdx.x & 127;
    int sub = threadIdx.x >> 7;
    const float invn = 1.f / NN;
    float mean = st[c] * invn;
    float var = fmaxf(st[128 + c] * invn - mean * mean, 0.f);
    float scv = g[c] * rsqrtf(var + EPSB);
    float shv = b[c] - mean * scv;
    int curg = -1;
    float s = 0.f, fmx = -INFINITY;
    for (int i = sub; i < 64; i += 2) {
        int r = r0 + i;
        if (r >= NN) break;
        int gr = bs[i];
        if (gr != curg) {
            if (curg >= 0) {
                atomicAdd(&psum[curg * 128 + c], s);
                atomicMax(&pmax[curg * 128 + c], fenc(fmx));
            }
            curg = gr; s = 0.f; fmx = -INFINITY;
        }
        float v = src[(size_t)r * 128 + c] * scv + shv + res[(size_t)r * 128 + c];
        s += v; fmx = fmaxf(fmx, v);
    }
    if (curg >= 0) {
        atomicAdd(&psum[curg * 128 + c], s);
        atomicMax(&pmax[curg * 128 + c], fenc(fmx));
    }
}

// ---------------- pooling phase 2: finalize ----------------
__global__ __launch_bounds__(128) void k_pool_final(const float* __restrict__ psum,
                                                    const unsigned* __restrict__ pmax,
                                                    const int* __restrict__ batch,
                                                    float* __restrict__ h) {
    __shared__ int se[2];
    int g = blockIdx.x;
    if (threadIdx.x == 0) {
        int lo = 0, hi = NN;
        while (lo < hi) { int mid = (lo + hi) >> 1; if (batch[mid] < g) lo = mid + 1; else hi = mid; }
        se[0] = lo;
        hi = NN;
        while (lo < hi) { int mid = (lo + hi) >> 1; if (batch[mid] < g + 1) lo = mid + 1; else hi = mid; }
        se[1] = lo;
    }
    __syncthreads();
    int cnt = se[1] - se[0];
    int c = threadIdx.x;
    float xm = psum[g * 128 + c] / fmaxf((float)cnt, 1.f);
    float xx = (cnt > 0) ? fdec(pmax[g * 128 + c]) : 0.f;
    h[g * 256 + c] = xm;
    h[g * 256 + 128 + c] = xx;
}

// ---------------- head ----------------
__global__ __launch_bounds__(128) void k_head1(const float* __restrict__ h,
                                               const float* __restrict__ W,
                                               const float* __restrict__ b,
                                               float* __restrict__ t1) {
    __shared__ float hr[256];
    int row = blockIdx.x;
    int t = threadIdx.x;
    hr[t] = h[row * 256 + t];
    hr[t + 128] = h[row * 256 + 128 + t];
    __syncthreads();
    float acc = b[t];
#pragma unroll 4
    for (int k = 0; k < 256; ++k) acc += hr[k] * W[k * 128 + t];
    t1[row * 128 + t] = acc;
}

__global__ __launch_bounds__(64) void k_head2(const float* __restrict__ t1,
                                              const float* __restrict__ st,
                                              const float* __restrict__ og,
                                              const float* __restrict__ obe,
                                              const float* __restrict__ W2,
                                              const float* __restrict__ b2,
                                              const float* __restrict__ W3,
                                              const float* __restrict__ b3,
                                              float* __restrict__ out) {
    __shared__ float v[128];
    int row = blockIdx.x, t = threadIdx.x;
    const float invn = 1.f / NG;
#pragma unroll
    for (int half = 0; half < 2; ++half) {
        int ch = t + half * 64;
        float mean = st[ch] * invn;
        float var = fmaxf(st[128 + ch] * invn - mean * mean, 0.f);
        float scv = og[ch] * rsqrtf(var + EPSB);
        float shv = obe[ch] - mean * scv;
        float a = t1[row * 128 + ch] * scv + shv;
        v[ch] = fmaxf(a, 0.f);
    }
    __syncthreads();
    float acc = b2[t];
#pragma unroll 4
    for (int k = 0; k < 128; ++k) acc += v[k] * W2[k * 64 + t];
    float p = fmaxf(acc, 0.f) * W3[t];
    p += __shfl_xor(p, 1); p += __shfl_xor(p, 2); p += __shfl_xor(p, 4);
    p += __shfl_xor(p, 8); p += __shfl_xor(p, 16); p += __shfl_xor(p, 32);
    if (t == 0) out[row] = p + b3[0];
}

// ---------------- launch ----------------
extern "C" void kernel_launch(void* const* d_in, const int* in_sizes, int n_in,
                              void* d_out, int out_size, void* d_ws, size_t ws_size,
                              hipStream_t stream) {
    const float* x_in   = (const float*)d_in[0];
    const int*   ei     = (const int*)d_in[1];
    const int*   batch  = (const int*)d_in[2];
    const float* emb_W  = (const float*)d_in[3];
    const float* emb_b  = (const float*)d_in[4];
    const float* emb_g  = (const float*)d_in[5];
    const float* emb_be = (const float*)d_in[6];
    const float* gWl    = (const float*)d_in[7];
    const float* gWr    = (const float*)d_in[8];
    const float* gbl    = (const float*)d_in[9];
    const float* gbr    = (const float*)d_in[10];
    const float* gatt   = (const float*)d_in[11];
    const float* gbias  = (const float*)d_in[12];
    const float* gg     = (const float*)d_in[13];
    const float* gbe    = (const float*)d_in[14];
    const float* tWq    = (const float*)d_in[15];
    const float* tWk    = (const float*)d_in[16];
    const float* tWv    = (const float*)d_in[17];
    const float* tWs    = (const float*)d_in[18];
    const float* tbq    = (const float*)d_in[19];
    const float* tbk    = (const float*)d_in[20];
    const float* tbv    = (const float*)d_in[21];
    const float* tbs    = (const float*)d_in[22];
    const float* tg     = (const float*)d_in[23];
    const float* tbe    = (const float*)d_in[24];
    const float* oW1    = (const float*)d_in[25];
    const float* ob1    = (const float*)d_in[26];
    const float* og     = (const float*)d_in[27];
    const float* obe    = (const float*)d_in[28];
    const float* oW2    = (const float*)d_in[29];
    const float* ob2    = (const float*)d_in[30];
    const float* oW3    = (const float*)d_in[31];
    const float* ob3    = (const float*)d_in[32];
    float* out = (float*)d_out;

    const size_t NDsz = (size_t)NN * 128;
    float* x     = (float*)d_ws;       // ping
    float* bA    = x + NDsz;           // pong (also emb out)
    float* bC    = bA + NDsz;          // aggr output / pre-BN
    float* stats = bC + NDsz;          // 7 * 256 floats
    float* hpool = stats + 7 * 256;    // 256*256
    float* t1    = hpool + 65536;      // 256*128
    float* scb   = t1 + 32768;         // hosts rank (NE ints)
    __half* xlh  = (__half*)(scb + (size_t)(NE + NN) * 4);  // xl / K
    __half* xrh  = xlh + NDsz;         // xr / Q
    __half* vh   = xrh + NDsz;         // V
    __half* sh   = vh + NDsz;          // S skip (fp16)
    short* Wt    = (short*)(sh + NDsz);  // 12 * 128*128 bf16 transposed
    int* deg     = (int*)(Wt + 12 * 16384);
    int* rp      = deg + NN;
    int* cursor  = rp + NN + 1;        // kept (dead) to preserve proven layout
    int2* edg    = (int2*)(cursor + NN);  // NE+64 packed (src,dst)
    int* bsum    = (int*)(edg + NE + 64);
    int* boff    = bsum + 256;
    float* psum  = (float*)(boff + 256);            // NG*128
    unsigned* pmax = (unsigned*)(psum + NG * 128);  // NG*128
    int* rank    = (int*)scb;          // aliases scb

    hipMemsetAsync(deg, 0, NN * sizeof(int), stream);
    hipMemsetAsync(stats, 0, 7 * 256 * sizeof(float), stream);
    hipMemsetAsync(psum, 0, NG * 128 * 2 * sizeof(float), stream);  // psum + pmax

    // weight prep (bf16 transposed)
    k_prep<<<12, 256, 0, stream>>>(gWl, gWr, tWq, tWk, tWv, tWs, Wt);

    // CSR by destination (rank-based; k_fill is atomic-free)
    const int S4 = (NE + 3) / 4;
    const int gQuarter = (S4 + 255) / 256;
    k_deg<<<gQuarter, 256, 0, stream>>>(ei, deg, rank);
    k_scan1<<<NB, 256, 0, stream>>>(deg, bsum);
    k_scan2<<<1, 256, 0, stream>>>(bsum, boff, rp);
    k_scan3<<<NB, 256, 0, stream>>>(deg, boff, rp);
    k_fill<<<gQuarter, 256, 0, stream>>>(ei, rp, rank, edg);

    const int gEmb  = (NN + 63) / 64;
    const int gGemm = (NN + 127) / 128;
    const int gStat = (NN + 127) / 128;
    const int gNode = (NN + 3) / 4;
    const int gPool = (NN + 63) / 64;

    // embedding GEMM -> bA; stats0
    k_gemm_emb<<<gEmb, 256, 0, stream>>>(x_in, emb_W, emb_b, bA, NN);
    k_stats<<<gStat, 256, 0, stream>>>(bA, NN, stats);

    // ping-pong feature buffers: residual source alternates x <-> bA
    k_gemm2bn<1, 1, 0, 1><<<gGemm, 256, 0, stream>>>(bA, nullptr, x, stats, emb_g, emb_be,
                                                     Wt + (size_t)0 * 16384, Wt + (size_t)4 * 16384,
                                                     gbl + 0 * 128, gbr + 0 * 128, xlh, xrh, NN);
    k_gat_aggr<<<gNode, 256, 0, stream>>>(xlh, xrh, gatt + 0 * 128, gbias + 0 * 128, rp, edg, bC);
    k_stats<<<gStat, 256, 0, stream>>>(bC, NN, stats + 1 * 256);
    k_gemm2bn<1, 1, 1, 1><<<gGemm, 256, 0, stream>>>(bC, x, bA, stats + 1 * 256, gg + 0 * 128, gbe + 0 * 128,
                                                     Wt + (size_t)1 * 16384, Wt + (size_t)5 * 16384,
                                                     gbl + 1 * 128, gbr + 1 * 128, xlh, xrh, NN);
    k_gat_aggr<<<gNode, 256, 0, stream>>>(xlh, xrh, gatt + 1 * 128, gbias + 1 * 128, rp, edg, bC);
    k_stats<<<gStat, 256, 0, stream>>>(bC, NN, stats + 2 * 256);
    k_gemm2bn<1, 1, 1, 1><<<gGemm, 256, 0, stream>>>(bC, bA, x, stats + 2 * 256, gg + 1 * 128, gbe + 1 * 128,
                                                     Wt + (size_t)2 * 16384, Wt + (size_t)6 * 16384,
                                                     gbl + 2 * 128, gbr + 2 * 128, xlh, xrh, NN);
    k_gat_aggr<<<gNode, 256, 0, stream>>>(xlh, xrh, gatt + 2 * 128, gbias + 2 * 128, rp, edg, bC);
    k_stats<<<gStat, 256, 0, stream>>>(bC, NN, stats + 3 * 256);
    k_gemm2bn<1, 1, 1, 1><<<gGemm, 256, 0, stream>>>(bC, x, bA, stats + 3 * 256, gg + 2 * 128, gbe + 2 * 128,
                                                     Wt + (size_t)3 * 16384, Wt + (size_t)7 * 16384,
                                                     gbl + 3 * 128, gbr + 3 * 128, xlh, xrh, NN);
    k_gat_aggr<<<gNode, 256, 0, stream>>>(xlh, xrh, gatt + 3 * 128, gbias + 3 * 128, rp, edg, bC);
    k_stats<<<gStat, 256, 0, stream>>>(bC, NN, stats + 4 * 256);

    // TransformerConv: ONE quad GEMM for Q/K/V/S (A staged once, xout written once)
    k_gemm4bn<<<gGemm, 256, 0, stream>>>(bC, bA, x, stats + 4 * 256, gg + 3 * 128, gbe + 3 * 128,
                                         Wt + (size_t)8 * 16384, tbq, tbk, tbv, tbs,
                                         xrh, xlh, vh, sh, NN);  // Q,K,V,S
    k_trans_aggr<<<gNode, 256, 0, stream>>>(xrh, xlh, vh, sh, rp, edg, bC);
    k_stats<<<gStat, 256, 0, stream>>>(bC, NN, stats + 5 * 256);

    // pooling (with fused final BN: v = bn(bC) + x) + head
    k_pool_part<<<gPool, 256, 0, stream>>>(bC, x, stats + 5 * 256, tg, tbe, batch, psum, pmax);
    k_pool_final<<<NG, 128, 0, stream>>>(psum, pmax, batch, hpool);
    k_head1<<<NG, 128, 0, stream>>>(hpool, oW1, ob1, t1);
    k_stats<<<(NG + 127) / 128, 256, 0, stream>>>(t1, NG, stats + 6 * 256);
    k_head2<<<NG, 64, 0, stream>>>(t1, stats + 6 * 256, og, obe, oW2, ob2, oW3, ob3, out);
}